// Round 4
// baseline (176.161 us; speedup 1.0000x reference)
//
#include <hip/hip_runtime.h>

// ---------------------------------------------------------------------------
// SelfCrossAttention: B=4, T=1024+1024, d=512, H=8, hd=64. fp32 I/O,
// bf16 MFMA internals.
// prep (X->bf16; W_self/W_cross -> wt[n][k], q section pre-scaled by
//       0.125*log2(e) so attention runs in exp2 domain; W_proj -> wtp[n][k])
//   -> qkv (SWAPPED-orientation 128x128 LDS GEMM: A=W rows, B=X rows ->
//           D[feature][token]; lane holds 4 consecutive features => Q/K
//           epilogue is one bf16x4 store per fragment (was 64 scalar 2B
//           stores/thread). V (1/3 of blocks) keeps per-token scalar stores
//           with the per-token window permutation.)
//   -> attn (round-2 config, measured 51.1us: GEMM-style LDS pipeline,
//            4 waves x 32q = 128q/block of one bh; all waves sweep all 2048
//            keys from double-buffered LDS K/V tiles staged via
//            global_load_lds with XOR bank-swizzle both-sides. exp2 softmax,
//            l via ones-A MFMA; direct normalized write, no merge.)
//   -> proj (swapped orientation too: f32x4 epilogue stores; 64(M)x128(N)
//            tile, grid 512 = 2 blocks/CU).
// ---------------------------------------------------------------------------

typedef short     bf16x8 __attribute__((ext_vector_type(8)));
typedef short     bf16x4 __attribute__((ext_vector_type(4)));
typedef float     f32x4  __attribute__((ext_vector_type(4)));
typedef int       i32x4  __attribute__((ext_vector_type(4)));

#define DI __device__ __forceinline__

DI unsigned short f2b(float f) {            // fp32 -> bf16 bits, RNE-ish
    union { float f; unsigned int u; } x; x.f = f;
    unsigned int r = x.u + 0x7fffu + ((x.u >> 16) & 1u);
    return (unsigned short)(r >> 16);
}
DI unsigned int fbits(float f) { union { float f; unsigned int u; } x; x.f = f; return x.u; }
DI float bitsf(unsigned int u) { union { unsigned int u; float f; } x; x.u = u; return x.f; }
DI float b2f(unsigned short v) { return bitsf(((unsigned int)v) << 16); }

DI void glds16(const unsigned short* g, unsigned short* l) {   // 16B global->LDS
    __builtin_amdgcn_global_load_lds(
        (const __attribute__((address_space(1))) void*)g,
        (__attribute__((address_space(3))) void*)l, 16, 0, 0);
}
DI void glds16i(const int* g, int* l) {
    __builtin_amdgcn_global_load_lds(
        (const __attribute__((address_space(1))) void*)g,
        (__attribute__((address_space(3))) void*)l, 16, 0, 0);
}

#define QSCALE 0.18033688011112042f   // 0.125 * log2(e): exp2-domain scores

// ---------------------------------------------------------------------------
// prep: [0,2048): X fp32 -> bf16 flat.
//       [2048,2432): W_self/W_cross -> wt[src][n][k], q-section * QSCALE
//       [2432,2496): W_proj -> wtp[n][k]
// ---------------------------------------------------------------------------
__global__ __launch_bounds__(256)
void prep_kernel(const float* __restrict__ Xs, const float* __restrict__ Xc,
                 const float* __restrict__ Ws, const float* __restrict__ Wc,
                 const float* __restrict__ Wp,
                 unsigned short* __restrict__ xb, unsigned short* __restrict__ wt,
                 unsigned short* __restrict__ wtp)
{
    const int bid = blockIdx.x, tid = threadIdx.x;
    if (bid < 2048) {
        int idx = bid * 2048 + tid * 8;
        const float* s = (idx < 2097152) ? (Xs + idx) : (Xc + idx - 2097152);
        f32x4 a0 = *(const f32x4*)s;
        f32x4 a1 = *(const f32x4*)(s + 4);
        bf16x8 v;
#pragma unroll
        for (int j = 0; j < 4; ++j) {
            ((unsigned short*)&v)[j]     = f2b(a0[j]);
            ((unsigned short*)&v)[4 + j] = f2b(a1[j]);
        }
        *(bf16x8*)(xb + idx) = v;
        return;
    }
    __shared__ unsigned short Tt[64 * 72];
    const float* W;
    unsigned short* dst;
    int k0, n0, ldn;
    float sc = 1.0f;
    if (bid < 2432) {
        int tj  = bid - 2048;
        int src = tj >= 192;  tj -= src * 192;
        k0  = (tj / 24) * 64;
        n0  = (tj % 24) * 64;
        W   = src ? Wc : Ws;
        ldn = 1536;
        dst = wt + (size_t)src * 786432;
        if (n0 < 512) sc = QSCALE;
    } else {
        int tj = bid - 2432;
        k0  = (tj >> 3) * 64;
        n0  = (tj & 7) * 64;
        W   = Wp;
        ldn = 512;
        dst = wtp;
    }
#pragma unroll
    for (int r = 0; r < 4; ++r) {
        int g  = tid + r * 256;
        int kr = g >> 4, nc4 = (g & 15) * 4;
        f32x4 v = *(const f32x4*)(W + (size_t)(k0 + kr) * ldn + n0 + nc4);
#pragma unroll
        for (int u = 0; u < 4; ++u)
            Tt[(nc4 + u) * 72 + kr] = f2b(v[u] * sc);
    }
    __syncthreads();
#pragma unroll
    for (int r = 0; r < 2; ++r) {
        int c = tid + r * 256;
        int nl = c >> 3, k8 = (c & 7) * 8;
        *(bf16x8*)(dst + (size_t)(n0 + nl) * 512 + k0 + k8) =
            *(const bf16x8*)(Tt + nl * 72 + k8);
    }
}

// ---------------------------------------------------------------------------
// QKV (swapped orientation): D[feature][token] = wt-rows . xb-rows^T + bias.
// 128(features) x 128(tokens) tile, 256 thr, glds-staged unpadded LDS.
// Lane holds 4 consecutive features at one token -> vectorized Q/K stores.
// q/k -> [bh][t][j] (bf16x4 stores); v -> vt[bh][j][t'] (scalar, per-token
// 32-window permutation pos = 2r - (r&3) - 28*(r>=16)).
// ---------------------------------------------------------------------------
__global__ __launch_bounds__(256)
void qkv_kernel(const unsigned short* __restrict__ xb,
                const unsigned short* __restrict__ wt,
                const float* __restrict__ bs, const float* __restrict__ bc,
                unsigned short* __restrict__ qb, unsigned short* __restrict__ kb,
                unsigned short* __restrict__ vtb)
{
    const int src = blockIdx.z;
    const int m0 = blockIdx.y * 128;    // feature tile (12)
    const int n0 = blockIdx.x * 128;    // token tile (32); x fastest: blocks
                                        // sharing the W A-tile are consecutive
    const float* bias = src ? bc : bs;
    const unsigned short* X = xb + (size_t)src * 2097152;
    const unsigned short* W = wt + (size_t)src * 786432;

    __shared__ unsigned short As[128 * 32];   // A = W (features)
    __shared__ unsigned short Bs[128 * 32];   // B = X (tokens)

    const int tid = threadIdx.x, lane = tid & 63, w = tid >> 6;
    const int quad = lane >> 4, r16 = lane & 15;
    const int mrow = (w >> 1) * 64, ncol = (w & 1) * 64;

    const f32x4 fz = {0.f, 0.f, 0.f, 0.f};
    f32x4 acc[4][4];
#pragma unroll
    for (int a = 0; a < 4; ++a)
#pragma unroll
        for (int b = 0; b < 4; ++b) acc[a][b] = fz;

    // glds staging: chunk ci covers rows [ci*16, ci*16+16); lane -> row/koff
    const int ci   = w << 1;
    const int rofs = lane >> 2, kofs = (lane & 3) * 8;
    const unsigned short* gA = W + (size_t)(m0 + ci * 16 + rofs) * 512 + kofs;
    const unsigned short* gB = X + (size_t)(n0 + ci * 16 + rofs) * 512 + kofs;
    unsigned short* lA = As + ci * 512 + lane * 8;
    unsigned short* lB = Bs + ci * 512 + lane * 8;

    for (int k0 = 0; k0 < 512; k0 += 32) {
        glds16(gA + k0, lA);
        glds16(gA + 16 * 512 + k0, lA + 512);
        glds16(gB + k0, lB);
        glds16(gB + 16 * 512 + k0, lB + 512);
        __syncthreads();

        bf16x8 af[4], bfr[4];
#pragma unroll
        for (int ms = 0; ms < 4; ++ms)
            af[ms] = *(const bf16x8*)(As + (mrow + ms * 16 + r16) * 32 + quad * 8);
#pragma unroll
        for (int ns = 0; ns < 4; ++ns)
            bfr[ns] = *(const bf16x8*)(Bs + (ncol + ns * 16 + r16) * 32 + quad * 8);
#pragma unroll
        for (int ms = 0; ms < 4; ++ms)
#pragma unroll
            for (int ns = 0; ns < 4; ++ns)
                acc[ms][ns] = __builtin_amdgcn_mfma_f32_16x16x32_bf16(
                    af[ms], bfr[ns], acc[ms][ns], 0, 0, 0);
        __syncthreads();
    }

    const int sec = m0 >> 9;    // 0=q,1=k,2=v (uniform per block)
#pragma unroll
    for (int ms = 0; ms < 4; ++ms) {
        const int f0 = m0 + mrow + ms * 16 + quad * 4;   // 4 consecutive feats
        const int hh = (f0 & 511) >> 6, j0 = f0 & 63;    // head, 4-aligned col
        f32x4 bb = *(const f32x4*)(bias + f0);
        if (sec == 0) bb = bb * QSCALE;
#pragma unroll
        for (int ns = 0; ns < 4; ++ns) {
            const int tcol = n0 + ncol + ns * 16 + r16;
            const int bi = tcol >> 10;
            const int tg = (tcol & 1023) + (src << 10);
            if (sec == 2) {                 // V: transposed + window-permuted
                const int r = tg & 31;
                const int pos = 2 * r - (r & 3) - ((r >> 4) * 28);
                const int tgp = (tg & ~31) + pos;
                unsigned short* vbase =
                    vtb + (((size_t)((bi * 8 + hh) * 64 + j0)) << 11) + tgp;
#pragma unroll
                for (int i = 0; i < 4; ++i)
                    vbase[(size_t)i << 11] = f2b(acc[ms][ns][i] + bb[i]);
            } else {
                unsigned short* dst = (sec == 0) ? qb : kb;
                bf16x4 pk;
#pragma unroll
                for (int i = 0; i < 4; ++i)
                    pk[i] = (short)f2b(acc[ms][ns][i] + bb[i]);
                *(bf16x4*)(dst + (((size_t)((bi * 8 + hh) * 2048 + tg)) << 6) + j0) = pk;
            }
        }
    }
}

// ---------------------------------------------------------------------------
// attn: S^T flash, exp2 domain, LDS-pipelined (round-2 config, 51.1us).
// Block 256 thr = 4 waves; block = 128 queries (32/wave) of one bh. All
// waves sweep all 2048 keys from double-buffered LDS tiles (64 keys):
// K 8KB + V 8KB per buffer, staged via global_load_lds with XOR swizzle
// slot^=(row&7) applied on the GLOBAL source (LDS dest linear, rule #21)
// and on the ds_read address. Key times staged once (8KB). l via ones-A
// MFMA; direct write, no merge. Grid 512 = 32 bh x 16 qtiles, XCD-swizzled.
// ---------------------------------------------------------------------------

// stage K+V chunks j = w*2, w*2+1 of tile T into buffer BB
#define STAGE(BB, T) do {                                                      \
    _Pragma("unroll")                                                          \
    for (int r_ = 0; r_ < 2; ++r_) {                                           \
        const int j_ = (w << 1) + r_;                                          \
        const int row_ = (j_ << 3) + rofs;                                     \
        glds16(Kg + (size_t)(((T) << 6) + row_) * 64 + lsw,                    \
               &Kl[BB][(j_ << 9) + lane * 8]);                                 \
        glds16(Vg + (size_t)row_ * 2048 + ((T) << 6) + lsw,                    \
               &Vl[BB][(j_ << 9) + lane * 8]);                                 \
    }                                                                          \
} while (0)

#define DOG(G, TQ, PF) do {                                                    \
    f32x4 s0_ = fz, s1_ = fz;                                                  \
    __builtin_amdgcn_s_setprio(1);                                             \
    s0_ = __builtin_amdgcn_mfma_f32_16x16x32_bf16(ka00, qf[G][0], s0_, 0, 0, 0); \
    s0_ = __builtin_amdgcn_mfma_f32_16x16x32_bf16(ka01, qf[G][1], s0_, 0, 0, 0); \
    s1_ = __builtin_amdgcn_mfma_f32_16x16x32_bf16(ka10, qf[G][0], s1_, 0, 0, 0); \
    s1_ = __builtin_amdgcn_mfma_f32_16x16x32_bf16(ka11, qf[G][1], s1_, 0, 0, 0); \
    __builtin_amdgcn_s_setprio(0);                                             \
    float e_[8];                                                               \
    _Pragma("unroll")                                                          \
    for (int i_ = 0; i_ < 4; ++i_) {                                           \
        float a0_ = ((TQ) >= tk0[i_]) ? s0_[i_] : -1e9f;                       \
        float a1_ = ((TQ) >= tk1[i_]) ? s1_[i_] : -1e9f;                       \
        e_[i_]     = __builtin_amdgcn_exp2f(a0_);                              \
        e_[4 + i_] = __builtin_amdgcn_exp2f(a1_);                              \
    }                                                                          \
    union { unsigned int d[4]; bf16x8 v; } pu_;                                \
    pu_.d[0] = __builtin_amdgcn_perm(fbits(e_[1]), fbits(e_[0]), 0x07060302u); \
    pu_.d[1] = __builtin_amdgcn_perm(fbits(e_[3]), fbits(e_[2]), 0x07060302u); \
    pu_.d[2] = __builtin_amdgcn_perm(fbits(e_[5]), fbits(e_[4]), 0x07060302u); \
    pu_.d[3] = __builtin_amdgcn_perm(fbits(e_[7]), fbits(e_[6]), 0x07060302u); \
    PF = pu_.v;                                                                \
    al[G] = __builtin_amdgcn_mfma_f32_16x16x32_bf16(ones, PF, al[G], 0, 0, 0); \
} while (0)

// one 64-key tile T from buffer BB: two 32-key windows
#define DOTILE(BB, T) do {                                                     \
    const unsigned short* Kb_ = Kl[BB];                                        \
    const unsigned short* Vb_ = Vl[BB];                                        \
    _Pragma("unroll")                                                          \
    for (int c_ = 0; c_ < 2; ++c_) {                                           \
        bf16x8 ka00 = *(const bf16x8*)(Kb_ + (c_ * 32 + r16) * 64 + ((quad ^ rsx) << 3));        \
        bf16x8 ka01 = *(const bf16x8*)(Kb_ + (c_ * 32 + r16) * 64 + (((quad + 4) ^ rsx) << 3));  \
        bf16x8 ka10 = *(const bf16x8*)(Kb_ + (c_ * 32 + 16 + r16) * 64 + ((quad ^ rsx) << 3));   \
        bf16x8 ka11 = *(const bf16x8*)(Kb_ + (c_ * 32 + 16 + r16) * 64 + (((quad + 4) ^ rsx) << 3)); \
        i32x4 tk0 = *(const i32x4*)(Ts + ((T) << 6) + c_ * 32 + quad * 4);     \
        i32x4 tk1 = *(const i32x4*)(Ts + ((T) << 6) + c_ * 32 + 16 + quad * 4);\
        const int vs_ = ((4 * c_ + quad) ^ rsx) << 3;                          \
        bf16x8 va0 = *(const bf16x8*)(Vb_ + (r16) * 64 + vs_);                 \
        bf16x8 va1 = *(const bf16x8*)(Vb_ + (16 + r16) * 64 + vs_);            \
        bf16x8 va2 = *(const bf16x8*)(Vb_ + (32 + r16) * 64 + vs_);            \
        bf16x8 va3 = *(const bf16x8*)(Vb_ + (48 + r16) * 64 + vs_);            \
        bf16x8 pf0, pf1;                                                       \
        DOG(0, tq0, pf0);                                                      \
        DOG(1, tq1, pf1);                                                      \
        __builtin_amdgcn_s_setprio(1);                                         \
        ot[0][0] = __builtin_amdgcn_mfma_f32_16x16x32_bf16(va0, pf0, ot[0][0], 0, 0, 0); \
        ot[1][0] = __builtin_amdgcn_mfma_f32_16x16x32_bf16(va0, pf1, ot[1][0], 0, 0, 0); \
        ot[0][1] = __builtin_amdgcn_mfma_f32_16x16x32_bf16(va1, pf0, ot[0][1], 0, 0, 0); \
        ot[1][1] = __builtin_amdgcn_mfma_f32_16x16x32_bf16(va1, pf1, ot[1][1], 0, 0, 0); \
        ot[0][2] = __builtin_amdgcn_mfma_f32_16x16x32_bf16(va2, pf0, ot[0][2], 0, 0, 0); \
        ot[1][2] = __builtin_amdgcn_mfma_f32_16x16x32_bf16(va2, pf1, ot[1][2], 0, 0, 0); \
        ot[0][3] = __builtin_amdgcn_mfma_f32_16x16x32_bf16(va3, pf0, ot[0][3], 0, 0, 0); \
        ot[1][3] = __builtin_amdgcn_mfma_f32_16x16x32_bf16(va3, pf1, ot[1][3], 0, 0, 0); \
        __builtin_amdgcn_s_setprio(0);                                         \
    }                                                                          \
} while (0)

__global__ __launch_bounds__(256, 2)
void attn_kernel(const unsigned short* __restrict__ qb,
                 const unsigned short* __restrict__ kb,
                 const unsigned short* __restrict__ vt,
                 const int* __restrict__ t_self, const int* __restrict__ t_cross,
                 unsigned short* __restrict__ y)
{
    const int bid = blockIdx.x;
    const int bh = ((bid & 7) << 2) | ((bid >> 3) & 3);   // XCD-local bh group
    const int qt = bid >> 5;                              // 0..15, 128 q each
    const int b = bh >> 3, h = bh & 7;
    const int tid = threadIdx.x, w = tid >> 6, lane = tid & 63;
    const int quad = lane >> 4, r16 = lane & 15;
    const int rofs = lane >> 3;                 // staging row-within-chunk
    const int lsw  = ((lane & 7) ^ rofs) << 3;  // pre-swizzled source slot (shorts)
    const int rsx  = r16 & 7;                   // read-side swizzle term

    const unsigned short* Q  = qb + (size_t)bh * 131072;
    const unsigned short* Kg = kb + (size_t)bh * 131072;
    const unsigned short* Vg = vt + (size_t)bh * 131072;
    const int* tsb = t_self + b * 1024;
    const int* tcb = t_cross + b * 1024;

    __shared__ unsigned short Kl[2][4096];   // 8KB per buffer, swizzled
    __shared__ unsigned short Vl[2][4096];   // 8KB per buffer, swizzled
    __shared__ int Ts[2048];                 // all key times (absolute)

    // stage all key times once: 8 x glds16 (2 per wave)
#pragma unroll
    for (int r = 0; r < 2; ++r) {
        const int sg = (w << 1) + r;
        const int* src = (sg < 4) ? (tsb + sg * 256) : (tcb + (sg - 4) * 256);
        glds16i(src + lane * 4, Ts + sg * 256 + lane * 4);
    }

    const int q0w = qt * 128 + w * 32;          // this wave's 32 queries
    bf16x8 qf[2][2];
#pragma unroll
    for (int g = 0; g < 2; ++g)
#pragma unroll
        for (int ks = 0; ks < 2; ++ks)
            qf[g][ks] = *(const bf16x8*)(Q + (size_t)(q0w + g * 16 + r16) * 64
                                           + ks * 32 + quad * 8);
    const int* tqp = (q0w < 1024) ? (tsb + q0w) : (tcb + (q0w - 1024));
    const int tq0 = tqp[r16];
    const int tq1 = tqp[16 + r16];

    const f32x4 fz = {0.f, 0.f, 0.f, 0.f};
    f32x4 ot[2][4], al[2];
#pragma unroll
    for (int g = 0; g < 2; ++g) {
        al[g] = fz;
#pragma unroll
        for (int nt = 0; nt < 4; ++nt) ot[g][nt] = fz;
    }
    const bf16x8 ones = {(short)0x3F80, (short)0x3F80, (short)0x3F80, (short)0x3F80,
                         (short)0x3F80, (short)0x3F80, (short)0x3F80, (short)0x3F80};

    STAGE(0, 0);
    __syncthreads();                            // times + tile 0 ready

    for (int T = 0; T < 32; T += 2) {
        STAGE(1, T + 1);                        // prefetch odd tile
        DOTILE(0, T);
        __syncthreads();                        // odd tile staged; buf0 free
        if (T + 2 < 32) STAGE(0, T + 2);        // prefetch next even tile
        DOTILE(1, T + 1);
        __syncthreads();                        // even tile staged; buf1 free
    }

    // epilogue: normalize and write y directly (no cross-wave merge)
#pragma unroll
    for (int g = 0; g < 2; ++g) {
        const float l = al[g][0];
        const float inv = (l > 0.f) ? (1.f / l) : 0.f;
        const size_t base = (((size_t)(b * 2048 + q0w + g * 16 + r16)) << 9) + h * 64;
#pragma unroll
        for (int nt = 0; nt < 4; ++nt) {
            bf16x4 pk;
#pragma unroll
            for (int i = 0; i < 4; ++i) pk[i] = (short)f2b(ot[g][nt][i] * inv);
            *(bf16x4*)(y + base + nt * 16 + quad * 4) = pk;
        }
    }
}

#undef STAGE
#undef DOG
#undef DOTILE

// ---------------------------------------------------------------------------
// proj (swapped orientation): D[feature][token] = wtp-rows . Y-rows^T + b.
// 64(features) x 128(tokens) tile -> grid 512 = 2 blocks/CU. Lane holds 4
// consecutive features at one token -> f32x4 epilogue stores (tuple split).
// ---------------------------------------------------------------------------
__global__ __launch_bounds__(256)
void proj_kernel(const unsigned short* __restrict__ X,
                 const unsigned short* __restrict__ Wt,
                 const float* __restrict__ bias,
                 float* __restrict__ out)
{
    const int m0 = blockIdx.y * 64;     // feature tile (8)
    const int n0 = blockIdx.x * 128;    // token tile (64)
    __shared__ unsigned short As[64 * 32];    // A = wtp (features)
    __shared__ unsigned short Bs[128 * 32];   // B = Y (tokens)

    const int tid = threadIdx.x, lane = tid & 63, w = tid >> 6;
    const int quad = lane >> 4, r16 = lane & 15;
    const int mrow = (w >> 1) * 32, ncol = (w & 1) * 64;

    const f32x4 fz = {0.f, 0.f, 0.f, 0.f};
    f32x4 acc[2][4];
#pragma unroll
    for (int a = 0; a < 2; ++a)
#pragma unroll
        for (int b = 0; b < 4; ++b) acc[a][b] = fz;

    // staging: A chunk w (16 rows), B chunks w*2, w*2+1
    const int rofs = lane >> 2, kofs = (lane & 3) * 8;
    const unsigned short* gA = Wt + (size_t)(m0 + w * 16 + rofs) * 512 + kofs;
    const unsigned short* gB = X + (size_t)(n0 + (w << 1) * 16 + rofs) * 512 + kofs;
    unsigned short* lA = As + w * 512 + lane * 8;
    unsigned short* lB = Bs + (w << 1) * 512 + lane * 8;

    for (int k0 = 0; k0 < 512; k0 += 32) {
        glds16(gA + k0, lA);
        glds16(gB + k0, lB);
        glds16(gB + 16 * 512 + k0, lB + 512);
        __syncthreads();

        bf16x8 af[2], bfr[4];
#pragma unroll
        for (int ms = 0; ms < 2; ++ms)
            af[ms] = *(const bf16x8*)(As + (mrow + ms * 16 + r16) * 32 + quad * 8);
#pragma unroll
        for (int ns = 0; ns < 4; ++ns)
            bfr[ns] = *(const bf16x8*)(Bs + (ncol + ns * 16 + r16) * 32 + quad * 8);
#pragma unroll
        for (int ms = 0; ms < 2; ++ms)
#pragma unroll
            for (int ns = 0; ns < 4; ++ns)
                acc[ms][ns] = __builtin_amdgcn_mfma_f32_16x16x32_bf16(
                    af[ms], bfr[ns], acc[ms][ns], 0, 0, 0);
        __syncthreads();
    }

#pragma unroll
    for (int ms = 0; ms < 2; ++ms) {
        const int f0 = m0 + mrow + ms * 16 + quad * 4;   // 4 consecutive feats
        f32x4 bb = *(const f32x4*)(bias + f0);
#pragma unroll
        for (int ns = 0; ns < 4; ++ns) {
            const int tok = n0 + ncol + ns * 16 + r16;
            const int bi = tok >> 11, t = tok & 2047;
            const size_t rowbase = (t < 1024)
                ? ((size_t)bi * 1024 + t) * 512
                : (size_t)2097152 + ((size_t)bi * 1024 + (t - 1024)) * 512;
            f32x4 v;
#pragma unroll
            for (int i = 0; i < 4; ++i) v[i] = acc[ms][ns][i] + bb[i];
            *(f32x4*)(out + rowbase + f0) = v;
        }
    }
}

// ---------------------------------------------------------------------------
extern "C" void kernel_launch(void* const* d_in, const int* in_sizes, int n_in,
                              void* d_out, int out_size, void* d_ws, size_t ws_size,
                              hipStream_t stream)
{
    const float* self_seq  = (const float*)d_in[0];
    const float* cross_seq = (const float*)d_in[1];
    const int*   t_self    = (const int*)d_in[2];
    const int*   t_cross   = (const int*)d_in[3];
    const float* W_self    = (const float*)d_in[4];
    const float* b_self    = (const float*)d_in[5];
    const float* W_cross   = (const float*)d_in[6];
    const float* b_cross   = (const float*)d_in[7];
    const float* W_proj    = (const float*)d_in[8];
    const float* b_proj    = (const float*)d_in[9];
    float* out = (float*)d_out;

    // ws (32 MB): q, k, vt, y (4 x 4,194,304 bf16).
    // d_out (33.5 MB fp32) slack holds xb (8 MB) + wt (3 MB) + wtp (0.5 MB)
    // as scratch until proj overwrites everything.
    unsigned short* qbuf = (unsigned short*)d_ws;
    unsigned short* kbuf = qbuf + 4194304;
    unsigned short* vtb  = kbuf + 4194304;
    unsigned short* ybuf = vtb + 4194304;
    unsigned short* xb   = (unsigned short*)d_out;
    unsigned short* wt   = xb + 4194304;
    unsigned short* wtp  = wt + 1572864;

    prep_kernel<<<dim3(2496), 256, 0, stream>>>(
        self_seq, cross_seq, W_self, W_cross, W_proj, xb, wt, wtp);

    qkv_kernel<<<dim3(32, 12, 2), 256, 0, stream>>>(
        xb, wt, b_self, b_cross, qbuf, kbuf, vtb);

    attn_kernel<<<dim3(512), 256, 0, stream>>>(
        qbuf, kbuf, vtb, t_self, t_cross, ybuf);

    proj_kernel<<<dim3(64, 8), 256, 0, stream>>>(
        ybuf, wtp, b_proj, out);
}

// Round 6
// 174.420 us; speedup vs baseline: 1.0100x; 1.0100x over previous
//
#include <hip/hip_runtime.h>

// ---------------------------------------------------------------------------
// SelfCrossAttention: B=4, T=1024+1024, d=512, H=8, hd=64. fp32 I/O,
// bf16 MFMA internals.
// prep (X->bf16; W_self/W_cross -> wt[n][k], q section pre-scaled by
//       0.125*log2(e) so attention runs in exp2 domain; W_proj -> wtp[n][k])
//   -> qkv (swapped-orientation 128x128 LDS GEMM, glds-staged; 2-bit XOR
//           k-slot swizzle both-sides kills the 8-way ds_read conflict of
//           the 64B-row LDS layout)
//   -> attn (round-2/4 config verbatim, measured 50.9-51.1us: GEMM-style
//            LDS pipeline, 4 waves x 32q = 128q/block of one bh; all waves
//            sweep all 2048 keys from double-buffered LDS K/V tiles staged
//            via global_load_lds with XOR bank-swizzle both-sides. exp2
//            softmax, l via ones-A MFMA; direct normalized write.)
//   -> proj (swapped orientation, 64x128 tile, f32x4 stores; same XOR
//            k-slot swizzle).
// ---------------------------------------------------------------------------

typedef short     bf16x8 __attribute__((ext_vector_type(8)));
typedef short     bf16x4 __attribute__((ext_vector_type(4)));
typedef float     f32x4  __attribute__((ext_vector_type(4)));
typedef int       i32x4  __attribute__((ext_vector_type(4)));

#define DI __device__ __forceinline__

DI unsigned short f2b(float f) {            // fp32 -> bf16 bits, RNE-ish
    union { float f; unsigned int u; } x; x.f = f;
    unsigned int r = x.u + 0x7fffu + ((x.u >> 16) & 1u);
    return (unsigned short)(r >> 16);
}
DI unsigned int fbits(float f) { union { float f; unsigned int u; } x; x.f = f; return x.u; }
DI float bitsf(unsigned int u) { union { unsigned int u; float f; } x; x.u = u; return x.f; }
DI float b2f(unsigned short v) { return bitsf(((unsigned int)v) << 16); }

DI void glds16(const unsigned short* g, unsigned short* l) {   // 16B global->LDS
    __builtin_amdgcn_global_load_lds(
        (const __attribute__((address_space(1))) void*)g,
        (__attribute__((address_space(3))) void*)l, 16, 0, 0);
}
DI void glds16i(const int* g, int* l) {
    __builtin_amdgcn_global_load_lds(
        (const __attribute__((address_space(1))) void*)g,
        (__attribute__((address_space(3))) void*)l, 16, 0, 0);
}

#define QSCALE 0.18033688011112042f   // 0.125 * log2(e): exp2-domain scores

// ---------------------------------------------------------------------------
// prep: [0,2048): X fp32 -> bf16 flat.
//       [2048,2432): W_self/W_cross -> wt[src][n][k], q-section * QSCALE
//       [2432,2496): W_proj -> wtp[n][k]
// ---------------------------------------------------------------------------
__global__ __launch_bounds__(256)
void prep_kernel(const float* __restrict__ Xs, const float* __restrict__ Xc,
                 const float* __restrict__ Ws, const float* __restrict__ Wc,
                 const float* __restrict__ Wp,
                 unsigned short* __restrict__ xb, unsigned short* __restrict__ wt,
                 unsigned short* __restrict__ wtp)
{
    const int bid = blockIdx.x, tid = threadIdx.x;
    if (bid < 2048) {
        int idx = bid * 2048 + tid * 8;
        const float* s = (idx < 2097152) ? (Xs + idx) : (Xc + idx - 2097152);
        f32x4 a0 = *(const f32x4*)s;
        f32x4 a1 = *(const f32x4*)(s + 4);
        bf16x8 v;
#pragma unroll
        for (int j = 0; j < 4; ++j) {
            ((unsigned short*)&v)[j]     = f2b(a0[j]);
            ((unsigned short*)&v)[4 + j] = f2b(a1[j]);
        }
        *(bf16x8*)(xb + idx) = v;
        return;
    }
    __shared__ unsigned short Tt[64 * 72];
    const float* W;
    unsigned short* dst;
    int k0, n0, ldn;
    float sc = 1.0f;
    if (bid < 2432) {
        int tj  = bid - 2048;
        int src = tj >= 192;  tj -= src * 192;
        k0  = (tj / 24) * 64;
        n0  = (tj % 24) * 64;
        W   = src ? Wc : Ws;
        ldn = 1536;
        dst = wt + (size_t)src * 786432;
        if (n0 < 512) sc = QSCALE;
    } else {
        int tj = bid - 2432;
        k0  = (tj >> 3) * 64;
        n0  = (tj & 7) * 64;
        W   = Wp;
        ldn = 512;
        dst = wtp;
    }
#pragma unroll
    for (int r = 0; r < 4; ++r) {
        int g  = tid + r * 256;
        int kr = g >> 4, nc4 = (g & 15) * 4;
        f32x4 v = *(const f32x4*)(W + (size_t)(k0 + kr) * ldn + n0 + nc4);
#pragma unroll
        for (int u = 0; u < 4; ++u)
            Tt[(nc4 + u) * 72 + kr] = f2b(v[u] * sc);
    }
    __syncthreads();
#pragma unroll
    for (int r = 0; r < 2; ++r) {
        int c = tid + r * 256;
        int nl = c >> 3, k8 = (c & 7) * 8;
        *(bf16x8*)(dst + (size_t)(n0 + nl) * 512 + k0 + k8) =
            *(const bf16x8*)(Tt + nl * 72 + k8);
    }
}

// ---------------------------------------------------------------------------
// QKV (swapped orientation): D[feature][token] = wt-rows . xb-rows^T + bias.
// 128(features) x 128(tokens) tile, glds-staged. LDS rows are 64B -> the
// plain layout is an 8-way ds_read_b128 conflict; fix with a 2-bit XOR of
// the 16B k-slot: physical slot p of row r holds logical slot p^((r>>1)&3).
// Applied on the GLOBAL source (LDS dest linear, rule #21) + on ds_read.
// ---------------------------------------------------------------------------
__global__ __launch_bounds__(256)
void qkv_kernel(const unsigned short* __restrict__ xb,
                const unsigned short* __restrict__ wt,
                const float* __restrict__ bs, const float* __restrict__ bc,
                unsigned short* __restrict__ qb, unsigned short* __restrict__ kb,
                unsigned short* __restrict__ vtb)
{
    const int src = blockIdx.z;
    const int m0 = blockIdx.y * 128;    // feature tile (12)
    const int n0 = blockIdx.x * 128;    // token tile (32)
    const float* bias = src ? bc : bs;
    const unsigned short* X = xb + (size_t)src * 2097152;
    const unsigned short* W = wt + (size_t)src * 786432;

    __shared__ unsigned short As[128 * 32];   // A = W (features)
    __shared__ unsigned short Bs[128 * 32];   // B = X (tokens)

    const int tid = threadIdx.x, lane = tid & 63, w = tid >> 6;
    const int quad = lane >> 4, r16 = lane & 15;
    const int mrow = (w >> 1) * 64, ncol = (w & 1) * 64;

    const f32x4 fz = {0.f, 0.f, 0.f, 0.f};
    f32x4 acc[4][4];
#pragma unroll
    for (int a = 0; a < 4; ++a)
#pragma unroll
        for (int b = 0; b < 4; ++b) acc[a][b] = fz;

    // glds staging: chunk ci covers rows [ci*16, ci*16+16); lane -> row/slot.
    // source k-chunk pre-swizzled: (lane&3) ^ ((lane>>3)&3)
    const int ci   = w << 1;
    const int rofs = lane >> 2;
    const int kswz = (((lane & 3) ^ ((lane >> 3) & 3))) * 8;
    const unsigned short* gA = W + (size_t)(m0 + ci * 16 + rofs) * 512 + kswz;
    const unsigned short* gB = X + (size_t)(n0 + ci * 16 + rofs) * 512 + kswz;
    unsigned short* lA = As + ci * 512 + lane * 8;
    unsigned short* lB = Bs + ci * 512 + lane * 8;
    const int rsw = (r16 >> 1) & 3;           // read-side slot swizzle

    for (int k0 = 0; k0 < 512; k0 += 32) {
        glds16(gA + k0, lA);
        glds16(gA + 16 * 512 + k0, lA + 512);
        glds16(gB + k0, lB);
        glds16(gB + 16 * 512 + k0, lB + 512);
        __syncthreads();

        bf16x8 af[4], bfr[4];
#pragma unroll
        for (int ms = 0; ms < 4; ++ms)
            af[ms] = *(const bf16x8*)(As + (mrow + ms * 16 + r16) * 32 + (quad ^ rsw) * 8);
#pragma unroll
        for (int ns = 0; ns < 4; ++ns)
            bfr[ns] = *(const bf16x8*)(Bs + (ncol + ns * 16 + r16) * 32 + (quad ^ rsw) * 8);
#pragma unroll
        for (int ms = 0; ms < 4; ++ms)
#pragma unroll
            for (int ns = 0; ns < 4; ++ns)
                acc[ms][ns] = __builtin_amdgcn_mfma_f32_16x16x32_bf16(
                    af[ms], bfr[ns], acc[ms][ns], 0, 0, 0);
        __syncthreads();
    }

    const int sec = m0 >> 9;    // 0=q,1=k,2=v (uniform per block)
#pragma unroll
    for (int ms = 0; ms < 4; ++ms) {
        const int f0 = m0 + mrow + ms * 16 + quad * 4;   // 4 consecutive feats
        const int hh = (f0 & 511) >> 6, j0 = f0 & 63;    // head, 4-aligned col
        f32x4 bb = *(const f32x4*)(bias + f0);
        if (sec == 0) bb = bb * QSCALE;
#pragma unroll
        for (int ns = 0; ns < 4; ++ns) {
            const int tcol = n0 + ncol + ns * 16 + r16;
            const int bi = tcol >> 10;
            const int tg = (tcol & 1023) + (src << 10);
            if (sec == 2) {                 // V: transposed + window-permuted
                const int r = tg & 31;
                const int pos = 2 * r - (r & 3) - ((r >> 4) * 28);
                const int tgp = (tg & ~31) + pos;
                unsigned short* vbase =
                    vtb + (((size_t)((bi * 8 + hh) * 64 + j0)) << 11) + tgp;
#pragma unroll
                for (int i = 0; i < 4; ++i)
                    vbase[(size_t)i << 11] = f2b(acc[ms][ns][i] + bb[i]);
            } else {
                unsigned short* dst = (sec == 0) ? qb : kb;
                bf16x4 pk;
#pragma unroll
                for (int i = 0; i < 4; ++i)
                    pk[i] = (short)f2b(acc[ms][ns][i] + bb[i]);
                *(bf16x4*)(dst + (((size_t)((bi * 8 + hh) * 2048 + tg)) << 6) + j0) = pk;
            }
        }
    }
}

// ---------------------------------------------------------------------------
// attn: S^T flash, exp2 domain, LDS-pipelined (round-2/4 config verbatim,
// 50.9-51.1us measured). Block 256 thr = 4 waves; block = 128 queries
// (32/wave) of one bh. All waves sweep all 2048 keys from double-buffered
// LDS tiles (64 keys): K 8KB + V 8KB per buffer, staged via global_load_lds
// with XOR swizzle slot^=(row&7) applied on the GLOBAL source (LDS dest
// linear, rule #21) and on the ds_read address. Key times staged once (8KB).
// l via ones-A MFMA; direct write, no merge. Grid 512 = 32 bh x 16 qtiles,
// XCD-swizzled; 2 blocks/CU.
// ---------------------------------------------------------------------------

// stage K+V chunks j = w*2, w*2+1 of tile T into buffer BB
#define STAGE(BB, T) do {                                                      \
    _Pragma("unroll")                                                          \
    for (int r_ = 0; r_ < 2; ++r_) {                                           \
        const int j_ = (w << 1) + r_;                                          \
        const int row_ = (j_ << 3) + rofs;                                     \
        glds16(Kg + (size_t)(((T) << 6) + row_) * 64 + lsw,                    \
               &Kl[BB][(j_ << 9) + lane * 8]);                                 \
        glds16(Vg + (size_t)row_ * 2048 + ((T) << 6) + lsw,                    \
               &Vl[BB][(j_ << 9) + lane * 8]);                                 \
    }                                                                          \
} while (0)

#define DOG(G, TQ, PF) do {                                                    \
    f32x4 s0_ = fz, s1_ = fz;                                                  \
    __builtin_amdgcn_s_setprio(1);                                             \
    s0_ = __builtin_amdgcn_mfma_f32_16x16x32_bf16(ka00, qf[G][0], s0_, 0, 0, 0); \
    s0_ = __builtin_amdgcn_mfma_f32_16x16x32_bf16(ka01, qf[G][1], s0_, 0, 0, 0); \
    s1_ = __builtin_amdgcn_mfma_f32_16x16x32_bf16(ka10, qf[G][0], s1_, 0, 0, 0); \
    s1_ = __builtin_amdgcn_mfma_f32_16x16x32_bf16(ka11, qf[G][1], s1_, 0, 0, 0); \
    __builtin_amdgcn_s_setprio(0);                                             \
    float e_[8];                                                               \
    _Pragma("unroll")                                                          \
    for (int i_ = 0; i_ < 4; ++i_) {                                           \
        float a0_ = ((TQ) >= tk0[i_]) ? s0_[i_] : -1e9f;                       \
        float a1_ = ((TQ) >= tk1[i_]) ? s1_[i_] : -1e9f;                       \
        e_[i_]     = __builtin_amdgcn_exp2f(a0_);                              \
        e_[4 + i_] = __builtin_amdgcn_exp2f(a1_);                              \
    }                                                                          \
    union { unsigned int d[4]; bf16x8 v; } pu_;                                \
    pu_.d[0] = __builtin_amdgcn_perm(fbits(e_[1]), fbits(e_[0]), 0x07060302u); \
    pu_.d[1] = __builtin_amdgcn_perm(fbits(e_[3]), fbits(e_[2]), 0x07060302u); \
    pu_.d[2] = __builtin_amdgcn_perm(fbits(e_[5]), fbits(e_[4]), 0x07060302u); \
    pu_.d[3] = __builtin_amdgcn_perm(fbits(e_[7]), fbits(e_[6]), 0x07060302u); \
    PF = pu_.v;                                                                \
    al[G] = __builtin_amdgcn_mfma_f32_16x16x32_bf16(ones, PF, al[G], 0, 0, 0); \
} while (0)

// one 64-key tile T from buffer BB: two 32-key windows
#define DOTILE(BB, T) do {                                                     \
    const unsigned short* Kb_ = Kl[BB];                                        \
    const unsigned short* Vb_ = Vl[BB];                                        \
    _Pragma("unroll")                                                          \
    for (int c_ = 0; c_ < 2; ++c_) {                                           \
        bf16x8 ka00 = *(const bf16x8*)(Kb_ + (c_ * 32 + r16) * 64 + ((quad ^ rsx) << 3));        \
        bf16x8 ka01 = *(const bf16x8*)(Kb_ + (c_ * 32 + r16) * 64 + (((quad + 4) ^ rsx) << 3));  \
        bf16x8 ka10 = *(const bf16x8*)(Kb_ + (c_ * 32 + 16 + r16) * 64 + ((quad ^ rsx) << 3));   \
        bf16x8 ka11 = *(const bf16x8*)(Kb_ + (c_ * 32 + 16 + r16) * 64 + (((quad + 4) ^ rsx) << 3)); \
        i32x4 tk0 = *(const i32x4*)(Ts + ((T) << 6) + c_ * 32 + quad * 4);     \
        i32x4 tk1 = *(const i32x4*)(Ts + ((T) << 6) + c_ * 32 + 16 + quad * 4);\
        const int vs_ = ((4 * c_ + quad) ^ rsx) << 3;                          \
        bf16x8 va0 = *(const bf16x8*)(Vb_ + (r16) * 64 + vs_);                 \
        bf16x8 va1 = *(const bf16x8*)(Vb_ + (16 + r16) * 64 + vs_);            \
        bf16x8 va2 = *(const bf16x8*)(Vb_ + (32 + r16) * 64 + vs_);            \
        bf16x8 va3 = *(const bf16x8*)(Vb_ + (48 + r16) * 64 + vs_);            \
        bf16x8 pf0, pf1;                                                       \
        DOG(0, tq0, pf0);                                                      \
        DOG(1, tq1, pf1);                                                      \
        __builtin_amdgcn_s_setprio(1);                                         \
        ot[0][0] = __builtin_amdgcn_mfma_f32_16x16x32_bf16(va0, pf0, ot[0][0], 0, 0, 0); \
        ot[1][0] = __builtin_amdgcn_mfma_f32_16x16x32_bf16(va0, pf1, ot[1][0], 0, 0, 0); \
        ot[0][1] = __builtin_amdgcn_mfma_f32_16x16x32_bf16(va1, pf0, ot[0][1], 0, 0, 0); \
        ot[1][1] = __builtin_amdgcn_mfma_f32_16x16x32_bf16(va1, pf1, ot[1][1], 0, 0, 0); \
        ot[0][2] = __builtin_amdgcn_mfma_f32_16x16x32_bf16(va2, pf0, ot[0][2], 0, 0, 0); \
        ot[1][2] = __builtin_amdgcn_mfma_f32_16x16x32_bf16(va2, pf1, ot[1][2], 0, 0, 0); \
        ot[0][3] = __builtin_amdgcn_mfma_f32_16x16x32_bf16(va3, pf0, ot[0][3], 0, 0, 0); \
        ot[1][3] = __builtin_amdgcn_mfma_f32_16x16x32_bf16(va3, pf1, ot[1][3], 0, 0, 0); \
        __builtin_amdgcn_s_setprio(0);                                         \
    }                                                                          \
} while (0)

__global__ __launch_bounds__(256, 2)
void attn_kernel(const unsigned short* __restrict__ qb,
                 const unsigned short* __restrict__ kb,
                 const unsigned short* __restrict__ vt,
                 const int* __restrict__ t_self, const int* __restrict__ t_cross,
                 unsigned short* __restrict__ y)
{
    const int bid = blockIdx.x;
    const int bh = ((bid & 7) << 2) | ((bid >> 3) & 3);   // XCD-local bh group
    const int qt = bid >> 5;                              // 0..15, 128 q each
    const int b = bh >> 3, h = bh & 7;
    const int tid = threadIdx.x, w = tid >> 6, lane = tid & 63;
    const int quad = lane >> 4, r16 = lane & 15;
    const int rofs = lane >> 3;                 // staging row-within-chunk
    const int lsw  = ((lane & 7) ^ rofs) << 3;  // pre-swizzled source slot (shorts)
    const int rsx  = r16 & 7;                   // read-side swizzle term

    const unsigned short* Q  = qb + (size_t)bh * 131072;
    const unsigned short* Kg = kb + (size_t)bh * 131072;
    const unsigned short* Vg = vt + (size_t)bh * 131072;
    const int* tsb = t_self + b * 1024;
    const int* tcb = t_cross + b * 1024;

    __shared__ unsigned short Kl[2][4096];   // 8KB per buffer, swizzled
    __shared__ unsigned short Vl[2][4096];   // 8KB per buffer, swizzled
    __shared__ int Ts[2048];                 // all key times (absolute)

    // stage all key times once: 8 x glds16 (2 per wave)
#pragma unroll
    for (int r = 0; r < 2; ++r) {
        const int sg = (w << 1) + r;
        const int* src = (sg < 4) ? (tsb + sg * 256) : (tcb + (sg - 4) * 256);
        glds16i(src + lane * 4, Ts + sg * 256 + lane * 4);
    }

    const int q0w = qt * 128 + w * 32;          // this wave's 32 queries
    bf16x8 qf[2][2];
#pragma unroll
    for (int g = 0; g < 2; ++g)
#pragma unroll
        for (int ks = 0; ks < 2; ++ks)
            qf[g][ks] = *(const bf16x8*)(Q + (size_t)(q0w + g * 16 + r16) * 64
                                           + ks * 32 + quad * 8);
    const int* tqp = (q0w < 1024) ? (tsb + q0w) : (tcb + (q0w - 1024));
    const int tq0 = tqp[r16];
    const int tq1 = tqp[16 + r16];

    const f32x4 fz = {0.f, 0.f, 0.f, 0.f};
    f32x4 ot[2][4], al[2];
#pragma unroll
    for (int g = 0; g < 2; ++g) {
        al[g] = fz;
#pragma unroll
        for (int nt = 0; nt < 4; ++nt) ot[g][nt] = fz;
    }
    const bf16x8 ones = {(short)0x3F80, (short)0x3F80, (short)0x3F80, (short)0x3F80,
                         (short)0x3F80, (short)0x3F80, (short)0x3F80, (short)0x3F80};

    STAGE(0, 0);
    __syncthreads();                            // times + tile 0 ready

    for (int T = 0; T < 32; T += 2) {
        STAGE(1, T + 1);                        // prefetch odd tile
        DOTILE(0, T);
        __syncthreads();                        // odd tile staged; buf0 free
        if (T + 2 < 32) STAGE(0, T + 2);        // prefetch next even tile
        DOTILE(1, T + 1);
        __syncthreads();                        // even tile staged; buf1 free
    }

    // epilogue: normalize and write y directly (no cross-wave merge)
#pragma unroll
    for (int g = 0; g < 2; ++g) {
        const float l = al[g][0];
        const float inv = (l > 0.f) ? (1.f / l) : 0.f;
        const size_t base = (((size_t)(b * 2048 + q0w + g * 16 + r16)) << 9) + h * 64;
#pragma unroll
        for (int nt = 0; nt < 4; ++nt) {
            bf16x4 pk;
#pragma unroll
            for (int i = 0; i < 4; ++i) pk[i] = (short)f2b(ot[g][nt][i] * inv);
            *(bf16x4*)(y + base + nt * 16 + quad * 4) = pk;
        }
    }
}

#undef STAGE
#undef DOG
#undef DOTILE

// ---------------------------------------------------------------------------
// proj (swapped orientation): D[feature][token] = wtp-rows . Y-rows^T + b.
// 64(features) x 128(tokens) tile -> grid 512 = 2 blocks/CU. f32x4 stores.
// Same 2-bit XOR k-slot swizzle as qkv.
// ---------------------------------------------------------------------------
__global__ __launch_bounds__(256)
void proj_kernel(const unsigned short* __restrict__ X,
                 const unsigned short* __restrict__ Wt,
                 const float* __restrict__ bias,
                 float* __restrict__ out)
{
    const int m0 = blockIdx.y * 64;     // feature tile (8)
    const int n0 = blockIdx.x * 128;    // token tile (64)
    __shared__ unsigned short As[64 * 32];    // A = wtp (features)
    __shared__ unsigned short Bs[128 * 32];   // B = Y (tokens)

    const int tid = threadIdx.x, lane = tid & 63, w = tid >> 6;
    const int quad = lane >> 4, r16 = lane & 15;
    const int mrow = (w >> 1) * 32, ncol = (w & 1) * 64;

    const f32x4 fz = {0.f, 0.f, 0.f, 0.f};
    f32x4 acc[2][4];
#pragma unroll
    for (int a = 0; a < 2; ++a)
#pragma unroll
        for (int b = 0; b < 4; ++b) acc[a][b] = fz;

    // staging: A chunk w (16 rows), B chunks w*2, w*2+1; source pre-swizzled
    const int rofs = lane >> 2;
    const int kswz = (((lane & 3) ^ ((lane >> 3) & 3))) * 8;
    const unsigned short* gA = Wt + (size_t)(m0 + w * 16 + rofs) * 512 + kswz;
    const unsigned short* gB = X + (size_t)(n0 + (w << 1) * 16 + rofs) * 512 + kswz;
    unsigned short* lA = As + w * 512 + lane * 8;
    unsigned short* lB = Bs + (w << 1) * 512 + lane * 8;
    const int rsw = (r16 >> 1) & 3;

    for (int k0 = 0; k0 < 512; k0 += 32) {
        glds16(gA + k0, lA);
        glds16(gB + k0, lB);
        glds16(gB + 16 * 512 + k0, lB + 512);
        __syncthreads();

        bf16x8 af[2], bfr[4];
#pragma unroll
        for (int ms = 0; ms < 2; ++ms)
            af[ms] = *(const bf16x8*)(As + (mrow + ms * 16 + r16) * 32 + (quad ^ rsw) * 8);
#pragma unroll
        for (int ns = 0; ns < 4; ++ns)
            bfr[ns] = *(const bf16x8*)(Bs + (ncol + ns * 16 + r16) * 32 + (quad ^ rsw) * 8);
#pragma unroll
        for (int ms = 0; ms < 2; ++ms)
#pragma unroll
            for (int ns = 0; ns < 4; ++ns)
                acc[ms][ns] = __builtin_amdgcn_mfma_f32_16x16x32_bf16(
                    af[ms], bfr[ns], acc[ms][ns], 0, 0, 0);
        __syncthreads();
    }

#pragma unroll
    for (int ms = 0; ms < 2; ++ms) {
        const int f0 = m0 + mrow + ms * 16 + quad * 4;   // 4 consecutive feats
        f32x4 bb = *(const f32x4*)(bias + f0);
#pragma unroll
        for (int ns = 0; ns < 4; ++ns) {
            const int tok = n0 + ncol + ns * 16 + r16;
            const int bi = tok >> 11, t = tok & 2047;
            const size_t rowbase = (t < 1024)
                ? ((size_t)bi * 1024 + t) * 512
                : (size_t)2097152 + ((size_t)bi * 1024 + (t - 1024)) * 512;
            f32x4 v;
#pragma unroll
            for (int i = 0; i < 4; ++i) v[i] = acc[ms][ns][i] + bb[i];
            *(f32x4*)(out + rowbase + f0) = v;
        }
    }
}

// ---------------------------------------------------------------------------
extern "C" void kernel_launch(void* const* d_in, const int* in_sizes, int n_in,
                              void* d_out, int out_size, void* d_ws, size_t ws_size,
                              hipStream_t stream)
{
    const float* self_seq  = (const float*)d_in[0];
    const float* cross_seq = (const float*)d_in[1];
    const int*   t_self    = (const int*)d_in[2];
    const int*   t_cross   = (const int*)d_in[3];
    const float* W_self    = (const float*)d_in[4];
    const float* b_self    = (const float*)d_in[5];
    const float* W_cross   = (const float*)d_in[6];
    const float* b_cross   = (const float*)d_in[7];
    const float* W_proj    = (const float*)d_in[8];
    const float* b_proj    = (const float*)d_in[9];
    float* out = (float*)d_out;

    // ws (32 MB): q, k, vt, y (4 x 4,194,304 bf16).
    // d_out (33.5 MB fp32) slack holds xb (8 MB) + wt (3 MB) + wtp (0.5 MB)
    // as scratch until proj overwrites everything.
    unsigned short* qbuf = (unsigned short*)d_ws;
    unsigned short* kbuf = qbuf + 4194304;
    unsigned short* vtb  = kbuf + 4194304;
    unsigned short* ybuf = vtb + 4194304;
    unsigned short* xb   = (unsigned short*)d_out;
    unsigned short* wt   = xb + 4194304;
    unsigned short* wtp  = wt + 1572864;

    prep_kernel<<<dim3(2496), 256, 0, stream>>>(
        self_seq, cross_seq, W_self, W_cross, W_proj, xb, wt, wtp);

    qkv_kernel<<<dim3(32, 12, 2), 256, 0, stream>>>(
        xb, wt, b_self, b_cross, qbuf, kbuf, vtb);

    attn_kernel<<<dim3(512), 256, 0, stream>>>(
        qbuf, kbuf, vtb, t_self, t_cross, ybuf);

    proj_kernel<<<dim3(64, 8), 256, 0, stream>>>(
        ybuf, wtp, b_proj, out);
}

// Round 8
// 171.577 us; speedup vs baseline: 1.0267x; 1.0166x over previous
//
#include <hip/hip_runtime.h>

// ---------------------------------------------------------------------------
// SelfCrossAttention: B=4, T=1024+1024, d=512, H=8, hd=64. fp32 I/O,
// bf16 MFMA internals.
// prep (X->bf16; W_self/W_cross -> wt[n][k], q section pre-scaled by
//       0.125*log2(e) so attention runs in exp2 domain; W_proj -> wtp[n][k])
//   -> qkv (swapped-orientation 128x128 LDS GEMM, glds-staged; 2-bit XOR
//           k-slot swizzle both-sides kills the 8-way ds_read conflict)
//   -> attn (round-6 verified STAGE/DOTILE macros BYTE-IDENTICAL; only the
//            orchestration changed: 4 LDS buffers, 2 tiles staged + 2 tiles
//            computed per __syncthreads interval -> barrier/drain events
//            33 -> 17. LDS 72KB, still 2 blocks/CU.)
//   -> proj (swapped orientation, 64x128 tile, f32x4 stores; XOR swizzle).
// ---------------------------------------------------------------------------

typedef short     bf16x8 __attribute__((ext_vector_type(8)));
typedef short     bf16x4 __attribute__((ext_vector_type(4)));
typedef float     f32x4  __attribute__((ext_vector_type(4)));
typedef int       i32x4  __attribute__((ext_vector_type(4)));

#define DI __device__ __forceinline__

DI unsigned short f2b(float f) {            // fp32 -> bf16 bits, RNE-ish
    union { float f; unsigned int u; } x; x.f = f;
    unsigned int r = x.u + 0x7fffu + ((x.u >> 16) & 1u);
    return (unsigned short)(r >> 16);
}
DI unsigned int fbits(float f) { union { float f; unsigned int u; } x; x.f = f; return x.u; }
DI float bitsf(unsigned int u) { union { unsigned int u; float f; } x; x.u = u; return x.f; }
DI float b2f(unsigned short v) { return bitsf(((unsigned int)v) << 16); }

DI void glds16(const unsigned short* g, unsigned short* l) {   // 16B global->LDS
    __builtin_amdgcn_global_load_lds(
        (const __attribute__((address_space(1))) void*)g,
        (__attribute__((address_space(3))) void*)l, 16, 0, 0);
}
DI void glds16i(const int* g, int* l) {
    __builtin_amdgcn_global_load_lds(
        (const __attribute__((address_space(1))) void*)g,
        (__attribute__((address_space(3))) void*)l, 16, 0, 0);
}

#define QSCALE 0.18033688011112042f   // 0.125 * log2(e): exp2-domain scores

// ---------------------------------------------------------------------------
// prep: [0,2048): X fp32 -> bf16 flat.
//       [2048,2432): W_self/W_cross -> wt[src][n][k], q-section * QSCALE
//       [2432,2496): W_proj -> wtp[n][k]
// ---------------------------------------------------------------------------
__global__ __launch_bounds__(256)
void prep_kernel(const float* __restrict__ Xs, const float* __restrict__ Xc,
                 const float* __restrict__ Ws, const float* __restrict__ Wc,
                 const float* __restrict__ Wp,
                 unsigned short* __restrict__ xb, unsigned short* __restrict__ wt,
                 unsigned short* __restrict__ wtp)
{
    const int bid = blockIdx.x, tid = threadIdx.x;
    if (bid < 2048) {
        int idx = bid * 2048 + tid * 8;
        const float* s = (idx < 2097152) ? (Xs + idx) : (Xc + idx - 2097152);
        f32x4 a0 = *(const f32x4*)s;
        f32x4 a1 = *(const f32x4*)(s + 4);
        bf16x8 v;
#pragma unroll
        for (int j = 0; j < 4; ++j) {
            ((unsigned short*)&v)[j]     = f2b(a0[j]);
            ((unsigned short*)&v)[4 + j] = f2b(a1[j]);
        }
        *(bf16x8*)(xb + idx) = v;
        return;
    }
    __shared__ unsigned short Tt[64 * 72];
    const float* W;
    unsigned short* dst;
    int k0, n0, ldn;
    float sc = 1.0f;
    if (bid < 2432) {
        int tj  = bid - 2048;
        int src = tj >= 192;  tj -= src * 192;
        k0  = (tj / 24) * 64;
        n0  = (tj % 24) * 64;
        W   = src ? Wc : Ws;
        ldn = 1536;
        dst = wt + (size_t)src * 786432;
        if (n0 < 512) sc = QSCALE;
    } else {
        int tj = bid - 2432;
        k0  = (tj >> 3) * 64;
        n0  = (tj & 7) * 64;
        W   = Wp;
        ldn = 512;
        dst = wtp;
    }
#pragma unroll
    for (int r = 0; r < 4; ++r) {
        int g  = tid + r * 256;
        int kr = g >> 4, nc4 = (g & 15) * 4;
        f32x4 v = *(const f32x4*)(W + (size_t)(k0 + kr) * ldn + n0 + nc4);
#pragma unroll
        for (int u = 0; u < 4; ++u)
            Tt[(nc4 + u) * 72 + kr] = f2b(v[u] * sc);
    }
    __syncthreads();
#pragma unroll
    for (int r = 0; r < 2; ++r) {
        int c = tid + r * 256;
        int nl = c >> 3, k8 = (c & 7) * 8;
        *(bf16x8*)(dst + (size_t)(n0 + nl) * 512 + k0 + k8) =
            *(const bf16x8*)(Tt + nl * 72 + k8);
    }
}

// ---------------------------------------------------------------------------
// QKV (swapped orientation): D[feature][token] = wt-rows . xb-rows^T + bias.
// 128(features) x 128(tokens) tile, glds-staged. 2-bit XOR of the 16B k-slot
// (source pre-swizzle + swizzled ds_read) kills the 8-way conflict.
// ---------------------------------------------------------------------------
__global__ __launch_bounds__(256)
void qkv_kernel(const unsigned short* __restrict__ xb,
                const unsigned short* __restrict__ wt,
                const float* __restrict__ bs, const float* __restrict__ bc,
                unsigned short* __restrict__ qb, unsigned short* __restrict__ kb,
                unsigned short* __restrict__ vtb)
{
    const int src = blockIdx.z;
    const int m0 = blockIdx.y * 128;    // feature tile (12)
    const int n0 = blockIdx.x * 128;    // token tile (32)
    const float* bias = src ? bc : bs;
    const unsigned short* X = xb + (size_t)src * 2097152;
    const unsigned short* W = wt + (size_t)src * 786432;

    __shared__ unsigned short As[128 * 32];   // A = W (features)
    __shared__ unsigned short Bs[128 * 32];   // B = X (tokens)

    const int tid = threadIdx.x, lane = tid & 63, w = tid >> 6;
    const int quad = lane >> 4, r16 = lane & 15;
    const int mrow = (w >> 1) * 64, ncol = (w & 1) * 64;

    const f32x4 fz = {0.f, 0.f, 0.f, 0.f};
    f32x4 acc[4][4];
#pragma unroll
    for (int a = 0; a < 4; ++a)
#pragma unroll
        for (int b = 0; b < 4; ++b) acc[a][b] = fz;

    const int ci   = w << 1;
    const int rofs = lane >> 2;
    const int kswz = (((lane & 3) ^ ((lane >> 3) & 3))) * 8;
    const unsigned short* gA = W + (size_t)(m0 + ci * 16 + rofs) * 512 + kswz;
    const unsigned short* gB = X + (size_t)(n0 + ci * 16 + rofs) * 512 + kswz;
    unsigned short* lA = As + ci * 512 + lane * 8;
    unsigned short* lB = Bs + ci * 512 + lane * 8;
    const int rsw = (r16 >> 1) & 3;           // read-side slot swizzle

    for (int k0 = 0; k0 < 512; k0 += 32) {
        glds16(gA + k0, lA);
        glds16(gA + 16 * 512 + k0, lA + 512);
        glds16(gB + k0, lB);
        glds16(gB + 16 * 512 + k0, lB + 512);
        __syncthreads();

        bf16x8 af[4], bfr[4];
#pragma unroll
        for (int ms = 0; ms < 4; ++ms)
            af[ms] = *(const bf16x8*)(As + (mrow + ms * 16 + r16) * 32 + (quad ^ rsw) * 8);
#pragma unroll
        for (int ns = 0; ns < 4; ++ns)
            bfr[ns] = *(const bf16x8*)(Bs + (ncol + ns * 16 + r16) * 32 + (quad ^ rsw) * 8);
#pragma unroll
        for (int ms = 0; ms < 4; ++ms)
#pragma unroll
            for (int ns = 0; ns < 4; ++ns)
                acc[ms][ns] = __builtin_amdgcn_mfma_f32_16x16x32_bf16(
                    af[ms], bfr[ns], acc[ms][ns], 0, 0, 0);
        __syncthreads();
    }

    const int sec = m0 >> 9;    // 0=q,1=k,2=v (uniform per block)
#pragma unroll
    for (int ms = 0; ms < 4; ++ms) {
        const int f0 = m0 + mrow + ms * 16 + quad * 4;   // 4 consecutive feats
        const int hh = (f0 & 511) >> 6, j0 = f0 & 63;    // head, 4-aligned col
        f32x4 bb = *(const f32x4*)(bias + f0);
        if (sec == 0) bb = bb * QSCALE;
#pragma unroll
        for (int ns = 0; ns < 4; ++ns) {
            const int tcol = n0 + ncol + ns * 16 + r16;
            const int bi = tcol >> 10;
            const int tg = (tcol & 1023) + (src << 10);
            if (sec == 2) {                 // V: transposed + window-permuted
                const int r = tg & 31;
                const int pos = 2 * r - (r & 3) - ((r >> 4) * 28);
                const int tgp = (tg & ~31) + pos;
                unsigned short* vbase =
                    vtb + (((size_t)((bi * 8 + hh) * 64 + j0)) << 11) + tgp;
#pragma unroll
                for (int i = 0; i < 4; ++i)
                    vbase[(size_t)i << 11] = f2b(acc[ms][ns][i] + bb[i]);
            } else {
                unsigned short* dst = (sec == 0) ? qb : kb;
                bf16x4 pk;
#pragma unroll
                for (int i = 0; i < 4; ++i)
                    pk[i] = (short)f2b(acc[ms][ns][i] + bb[i]);
                *(bf16x4*)(dst + (((size_t)((bi * 8 + hh) * 2048 + tg)) << 6) + j0) = pk;
            }
        }
    }
}

// ---------------------------------------------------------------------------
// attn: S^T flash, exp2 domain, LDS-pipelined. STAGE/DOTILE macros are
// byte-identical to the thrice-verified round-6 kernel (64-key tiles, same
// chunk mapping, same XOR swizzles). Only orchestration changed: 4 buffers,
// 2 tiles staged + 2 computed per __syncthreads interval (17 barriers vs 33).
// Block 256 thr = 4 waves; block = 128 queries (32/wave) of one bh.
// Key times staged once (8KB). l via ones-A MFMA; direct write, no merge.
// Grid 512 = 32 bh x 16 qtiles, XCD-swizzled; LDS 72KB -> 2 blocks/CU.
// ---------------------------------------------------------------------------

// stage K+V chunks j = w*2, w*2+1 of tile T into buffer BB
#define STAGE(BB, T) do {                                                      \
    _Pragma("unroll")                                                          \
    for (int r_ = 0; r_ < 2; ++r_) {                                           \
        const int j_ = (w << 1) + r_;                                          \
        const int row_ = (j_ << 3) + rofs;                                     \
        glds16(Kg + (size_t)(((T) << 6) + row_) * 64 + lsw,                    \
               &Kl[BB][(j_ << 9) + lane * 8]);                                 \
        glds16(Vg + (size_t)row_ * 2048 + ((T) << 6) + lsw,                    \
               &Vl[BB][(j_ << 9) + lane * 8]);                                 \
    }                                                                          \
} while (0)

#define DOG(G, TQ, PF) do {                                                    \
    f32x4 s0_ = fz, s1_ = fz;                                                  \
    __builtin_amdgcn_s_setprio(1);                                             \
    s0_ = __builtin_amdgcn_mfma_f32_16x16x32_bf16(ka00, qf[G][0], s0_, 0, 0, 0); \
    s0_ = __builtin_amdgcn_mfma_f32_16x16x32_bf16(ka01, qf[G][1], s0_, 0, 0, 0); \
    s1_ = __builtin_amdgcn_mfma_f32_16x16x32_bf16(ka10, qf[G][0], s1_, 0, 0, 0); \
    s1_ = __builtin_amdgcn_mfma_f32_16x16x32_bf16(ka11, qf[G][1], s1_, 0, 0, 0); \
    __builtin_amdgcn_s_setprio(0);                                             \
    float e_[8];                                                               \
    _Pragma("unroll")                                                          \
    for (int i_ = 0; i_ < 4; ++i_) {                                           \
        float a0_ = ((TQ) >= tk0[i_]) ? s0_[i_] : -1e9f;                       \
        float a1_ = ((TQ) >= tk1[i_]) ? s1_[i_] : -1e9f;                       \
        e_[i_]     = __builtin_amdgcn_exp2f(a0_);                              \
        e_[4 + i_] = __builtin_amdgcn_exp2f(a1_);                              \
    }                                                                          \
    union { unsigned int d[4]; bf16x8 v; } pu_;                                \
    pu_.d[0] = __builtin_amdgcn_perm(fbits(e_[1]), fbits(e_[0]), 0x07060302u); \
    pu_.d[1] = __builtin_amdgcn_perm(fbits(e_[3]), fbits(e_[2]), 0x07060302u); \
    pu_.d[2] = __builtin_amdgcn_perm(fbits(e_[5]), fbits(e_[4]), 0x07060302u); \
    pu_.d[3] = __builtin_amdgcn_perm(fbits(e_[7]), fbits(e_[6]), 0x07060302u); \
    PF = pu_.v;                                                                \
    al[G] = __builtin_amdgcn_mfma_f32_16x16x32_bf16(ones, PF, al[G], 0, 0, 0); \
} while (0)

// one 64-key tile T from buffer BB: two 32-key windows
#define DOTILE(BB, T) do {                                                     \
    const unsigned short* Kb_ = Kl[BB];                                        \
    const unsigned short* Vb_ = Vl[BB];                                        \
    _Pragma("unroll")                                                          \
    for (int c_ = 0; c_ < 2; ++c_) {                                           \
        bf16x8 ka00 = *(const bf16x8*)(Kb_ + (c_ * 32 + r16) * 64 + ((quad ^ rsx) << 3));        \
        bf16x8 ka01 = *(const bf16x8*)(Kb_ + (c_ * 32 + r16) * 64 + (((quad + 4) ^ rsx) << 3));  \
        bf16x8 ka10 = *(const bf16x8*)(Kb_ + (c_ * 32 + 16 + r16) * 64 + ((quad ^ rsx) << 3));   \
        bf16x8 ka11 = *(const bf16x8*)(Kb_ + (c_ * 32 + 16 + r16) * 64 + (((quad + 4) ^ rsx) << 3)); \
        i32x4 tk0 = *(const i32x4*)(Ts + ((T) << 6) + c_ * 32 + quad * 4);     \
        i32x4 tk1 = *(const i32x4*)(Ts + ((T) << 6) + c_ * 32 + 16 + quad * 4);\
        const int vs_ = ((4 * c_ + quad) ^ rsx) << 3;                          \
        bf16x8 va0 = *(const bf16x8*)(Vb_ + (r16) * 64 + vs_);                 \
        bf16x8 va1 = *(const bf16x8*)(Vb_ + (16 + r16) * 64 + vs_);            \
        bf16x8 va2 = *(const bf16x8*)(Vb_ + (32 + r16) * 64 + vs_);            \
        bf16x8 va3 = *(const bf16x8*)(Vb_ + (48 + r16) * 64 + vs_);            \
        bf16x8 pf0, pf1;                                                       \
        DOG(0, tq0, pf0);                                                      \
        DOG(1, tq1, pf1);                                                      \
        __builtin_amdgcn_s_setprio(1);                                         \
        ot[0][0] = __builtin_amdgcn_mfma_f32_16x16x32_bf16(va0, pf0, ot[0][0], 0, 0, 0); \
        ot[1][0] = __builtin_amdgcn_mfma_f32_16x16x32_bf16(va0, pf1, ot[1][0], 0, 0, 0); \
        ot[0][1] = __builtin_amdgcn_mfma_f32_16x16x32_bf16(va1, pf0, ot[0][1], 0, 0, 0); \
        ot[1][1] = __builtin_amdgcn_mfma_f32_16x16x32_bf16(va1, pf1, ot[1][1], 0, 0, 0); \
        ot[0][2] = __builtin_amdgcn_mfma_f32_16x16x32_bf16(va2, pf0, ot[0][2], 0, 0, 0); \
        ot[1][2] = __builtin_amdgcn_mfma_f32_16x16x32_bf16(va2, pf1, ot[1][2], 0, 0, 0); \
        ot[0][3] = __builtin_amdgcn_mfma_f32_16x16x32_bf16(va3, pf0, ot[0][3], 0, 0, 0); \
        ot[1][3] = __builtin_amdgcn_mfma_f32_16x16x32_bf16(va3, pf1, ot[1][3], 0, 0, 0); \
        __builtin_amdgcn_s_setprio(0);                                         \
    }                                                                          \
} while (0)

__global__ __launch_bounds__(256, 2)
void attn_kernel(const unsigned short* __restrict__ qb,
                 const unsigned short* __restrict__ kb,
                 const unsigned short* __restrict__ vt,
                 const int* __restrict__ t_self, const int* __restrict__ t_cross,
                 unsigned short* __restrict__ y)
{
    const int bid = blockIdx.x;
    const int bh = ((bid & 7) << 2) | ((bid >> 3) & 3);   // XCD-local bh group
    const int qt = bid >> 5;                              // 0..15, 128 q each
    const int b = bh >> 3, h = bh & 7;
    const int tid = threadIdx.x, w = tid >> 6, lane = tid & 63;
    const int quad = lane >> 4, r16 = lane & 15;
    const int rofs = lane >> 3;                 // staging row-within-chunk
    const int lsw  = ((lane & 7) ^ rofs) << 3;  // pre-swizzled source slot (shorts)
    const int rsx  = r16 & 7;                   // read-side swizzle term

    const unsigned short* Q  = qb + (size_t)bh * 131072;
    const unsigned short* Kg = kb + (size_t)bh * 131072;
    const unsigned short* Vg = vt + (size_t)bh * 131072;
    const int* tsb = t_self + b * 1024;
    const int* tcb = t_cross + b * 1024;

    __shared__ unsigned short Kl[4][4096];   // 8KB per buffer, swizzled
    __shared__ unsigned short Vl[4][4096];   // 8KB per buffer, swizzled
    __shared__ int Ts[2048];                 // all key times (absolute)

    // stage all key times once: 8 x glds16 (2 per wave)
#pragma unroll
    for (int r = 0; r < 2; ++r) {
        const int sg = (w << 1) + r;
        const int* src = (sg < 4) ? (tsb + sg * 256) : (tcb + (sg - 4) * 256);
        glds16i(src + lane * 4, Ts + sg * 256 + lane * 4);
    }

    const int q0w = qt * 128 + w * 32;          // this wave's 32 queries
    bf16x8 qf[2][2];
#pragma unroll
    for (int g = 0; g < 2; ++g)
#pragma unroll
        for (int ks = 0; ks < 2; ++ks)
            qf[g][ks] = *(const bf16x8*)(Q + (size_t)(q0w + g * 16 + r16) * 64
                                           + ks * 32 + quad * 8);
    const int* tqp = (q0w < 1024) ? (tsb + q0w) : (tcb + (q0w - 1024));
    const int tq0 = tqp[r16];
    const int tq1 = tqp[16 + r16];

    const f32x4 fz = {0.f, 0.f, 0.f, 0.f};
    f32x4 ot[2][4], al[2];
#pragma unroll
    for (int g = 0; g < 2; ++g) {
        al[g] = fz;
#pragma unroll
        for (int nt = 0; nt < 4; ++nt) ot[g][nt] = fz;
    }
    const bf16x8 ones = {(short)0x3F80, (short)0x3F80, (short)0x3F80, (short)0x3F80,
                         (short)0x3F80, (short)0x3F80, (short)0x3F80, (short)0x3F80};

    STAGE(0, 0);
    STAGE(1, 1);
    __syncthreads();                            // times + tiles 0,1 ready

    for (int T = 0; T < 32; T += 4) {
        STAGE(2, T + 2);                        // prefetch next pair
        STAGE(3, T + 3);
        DOTILE(0, T);
        DOTILE(1, T + 1);
        __syncthreads();                        // pair {2,3} staged; {0,1} free
        if (T + 4 < 32) {
            STAGE(0, T + 4);
            STAGE(1, T + 5);
        }
        DOTILE(2, T + 2);
        DOTILE(3, T + 3);
        __syncthreads();                        // pair {0,1} staged; {2,3} free
    }

    // epilogue: normalize and write y directly (no cross-wave merge)
#pragma unroll
    for (int g = 0; g < 2; ++g) {
        const float l = al[g][0];
        const float inv = (l > 0.f) ? (1.f / l) : 0.f;
        const size_t base = (((size_t)(b * 2048 + q0w + g * 16 + r16)) << 9) + h * 64;
#pragma unroll
        for (int nt = 0; nt < 4; ++nt) {
            bf16x4 pk;
#pragma unroll
            for (int i = 0; i < 4; ++i) pk[i] = (short)f2b(ot[g][nt][i] * inv);
            *(bf16x4*)(y + base + nt * 16 + quad * 4) = pk;
        }
    }
}

#undef STAGE
#undef DOG
#undef DOTILE

// ---------------------------------------------------------------------------
// proj (swapped orientation): D[feature][token] = wtp-rows . Y-rows^T + b.
// 64(features) x 128(tokens) tile -> grid 512 = 2 blocks/CU. f32x4 stores.
// Same 2-bit XOR k-slot swizzle as qkv.
// ---------------------------------------------------------------------------
__global__ __launch_bounds__(256)
void proj_kernel(const unsigned short* __restrict__ X,
                 const unsigned short* __restrict__ Wt,
                 const float* __restrict__ bias,
                 float* __restrict__ out)
{
    const int m0 = blockIdx.y * 64;     // feature tile (8)
    const int n0 = blockIdx.x * 128;    // token tile (64)
    __shared__ unsigned short As[64 * 32];    // A = wtp (features)
    __shared__ unsigned short Bs[128 * 32];   // B = Y (tokens)

    const int tid = threadIdx.x, lane = tid & 63, w = tid >> 6;
    const int quad = lane >> 4, r16 = lane & 15;
    const int mrow = (w >> 1) * 32, ncol = (w & 1) * 64;

    const f32x4 fz = {0.f, 0.f, 0.f, 0.f};
    f32x4 acc[2][4];
#pragma unroll
    for (int a = 0; a < 2; ++a)
#pragma unroll
        for (int b = 0; b < 4; ++b) acc[a][b] = fz;

    const int rofs = lane >> 2;
    const int kswz = (((lane & 3) ^ ((lane >> 3) & 3))) * 8;
    const unsigned short* gA = Wt + (size_t)(m0 + w * 16 + rofs) * 512 + kswz;
    const unsigned short* gB = X + (size_t)(n0 + (w << 1) * 16 + rofs) * 512 + kswz;
    unsigned short* lA = As + w * 512 + lane * 8;
    unsigned short* lB = Bs + (w << 1) * 512 + lane * 8;
    const int rsw = (r16 >> 1) & 3;

    for (int k0 = 0; k0 < 512; k0 += 32) {
        glds16(gA + k0, lA);
        glds16(gB + k0, lB);
        glds16(gB + 16 * 512 + k0, lB + 512);
        __syncthreads();

        bf16x8 af[2], bfr[4];
#pragma unroll
        for (int ms = 0; ms < 2; ++ms)
            af[ms] = *(const bf16x8*)(As + (mrow + ms * 16 + r16) * 32 + (quad ^ rsw) * 8);
#pragma unroll
        for (int ns = 0; ns < 4; ++ns)
            bfr[ns] = *(const bf16x8*)(Bs + (ncol + ns * 16 + r16) * 32 + (quad ^ rsw) * 8);
#pragma unroll
        for (int ms = 0; ms < 2; ++ms)
#pragma unroll
            for (int ns = 0; ns < 4; ++ns)
                acc[ms][ns] = __builtin_amdgcn_mfma_f32_16x16x32_bf16(
                    af[ms], bfr[ns], acc[ms][ns], 0, 0, 0);
        __syncthreads();
    }

#pragma unroll
    for (int ms = 0; ms < 2; ++ms) {
        const int f0 = m0 + mrow + ms * 16 + quad * 4;   // 4 consecutive feats
        f32x4 bb = *(const f32x4*)(bias + f0);
#pragma unroll
        for (int ns = 0; ns < 4; ++ns) {
            const int tok = n0 + ncol + ns * 16 + r16;
            const int bi = tok >> 11, t = tok & 2047;
            const size_t rowbase = (t < 1024)
                ? ((size_t)bi * 1024 + t) * 512
                : (size_t)2097152 + ((size_t)bi * 1024 + (t - 1024)) * 512;
            f32x4 v;
#pragma unroll
            for (int i = 0; i < 4; ++i) v[i] = acc[ms][ns][i] + bb[i];
            *(f32x4*)(out + rowbase + f0) = v;
        }
    }
}

// ---------------------------------------------------------------------------
extern "C" void kernel_launch(void* const* d_in, const int* in_sizes, int n_in,
                              void* d_out, int out_size, void* d_ws, size_t ws_size,
                              hipStream_t stream)
{
    const float* self_seq  = (const float*)d_in[0];
    const float* cross_seq = (const float*)d_in[1];
    const int*   t_self    = (const int*)d_in[2];
    const int*   t_cross   = (const int*)d_in[3];
    const float* W_self    = (const float*)d_in[4];
    const float* b_self    = (const float*)d_in[5];
    const float* W_cross   = (const float*)d_in[6];
    const float* b_cross   = (const float*)d_in[7];
    const float* W_proj    = (const float*)d_in[8];
    const float* b_proj    = (const float*)d_in[9];
    float* out = (float*)d_out;

    // ws (32 MB): q, k, vt, y (4 x 4,194,304 bf16).
    // d_out (33.5 MB fp32) slack holds xb (8 MB) + wt (3 MB) + wtp (0.5 MB)
    // as scratch until proj overwrites everything.
    unsigned short* qbuf = (unsigned short*)d_ws;
    unsigned short* kbuf = qbuf + 4194304;
    unsigned short* vtb  = kbuf + 4194304;
    unsigned short* ybuf = vtb + 4194304;
    unsigned short* xb   = (unsigned short*)d_out;
    unsigned short* wt   = xb + 4194304;
    unsigned short* wtp  = wt + 1572864;

    prep_kernel<<<dim3(2496), 256, 0, stream>>>(
        self_seq, cross_seq, W_self, W_cross, W_proj, xb, wt, wtp);

    qkv_kernel<<<dim3(32, 12, 2), 256, 0, stream>>>(
        xb, wt, b_self, b_cross, qbuf, kbuf, vtb);

    attn_kernel<<<dim3(512), 256, 0, stream>>>(
        qbuf, kbuf, vtb, t_self, t_cross, ybuf);

    proj_kernel<<<dim3(64, 8), 256, 0, stream>>>(
        ybuf, wtp, b_proj, out);
}

// Round 9
// 169.553 us; speedup vs baseline: 1.0390x; 1.0119x over previous
//
#include <hip/hip_runtime.h>

// ---------------------------------------------------------------------------
// SelfCrossAttention: B=4, T=1024+1024, d=512, H=8, hd=64. fp32 I/O,
// bf16 MFMA internals.
// prep (X->bf16; W_self/W_cross -> wt[n][k], q section pre-scaled by
//       0.125*log2(e) so attention runs in exp2 domain; W_proj -> wtp[n][k])
//   -> qkv (swapped-orientation 128x128 LDS GEMM; NEW: double-buffered LDS
//           with prefetch-ahead orchestration (the 5x-verified attn pattern):
//           stage k+1 while computing k. 32KB LDS. XOR k-slot swizzle kept.)
//   -> attn (round-8 verified: 4-buffer pairing, 2 tiles staged + 2 computed
//            per barrier interval, 64-key tiles, XOR swizzles, exp2 softmax,
//            l via ones-A MFMA, direct write. 72KB LDS.)
//   -> proj (swapped orientation, 64x128 tile; NEW: same double-buffered
//            prefetch orchestration. 24KB LDS.)
// ---------------------------------------------------------------------------

typedef short     bf16x8 __attribute__((ext_vector_type(8)));
typedef short     bf16x4 __attribute__((ext_vector_type(4)));
typedef float     f32x4  __attribute__((ext_vector_type(4)));
typedef int       i32x4  __attribute__((ext_vector_type(4)));

#define DI __device__ __forceinline__

DI unsigned short f2b(float f) {            // fp32 -> bf16 bits, RNE-ish
    union { float f; unsigned int u; } x; x.f = f;
    unsigned int r = x.u + 0x7fffu + ((x.u >> 16) & 1u);
    return (unsigned short)(r >> 16);
}
DI unsigned int fbits(float f) { union { float f; unsigned int u; } x; x.f = f; return x.u; }
DI float bitsf(unsigned int u) { union { unsigned int u; float f; } x; x.u = u; return x.f; }
DI float b2f(unsigned short v) { return bitsf(((unsigned int)v) << 16); }

DI void glds16(const unsigned short* g, unsigned short* l) {   // 16B global->LDS
    __builtin_amdgcn_global_load_lds(
        (const __attribute__((address_space(1))) void*)g,
        (__attribute__((address_space(3))) void*)l, 16, 0, 0);
}
DI void glds16i(const int* g, int* l) {
    __builtin_amdgcn_global_load_lds(
        (const __attribute__((address_space(1))) void*)g,
        (__attribute__((address_space(3))) void*)l, 16, 0, 0);
}

#define QSCALE 0.18033688011112042f   // 0.125 * log2(e): exp2-domain scores

// ---------------------------------------------------------------------------
// prep: [0,2048): X fp32 -> bf16 flat.
//       [2048,2432): W_self/W_cross -> wt[src][n][k], q-section * QSCALE
//       [2432,2496): W_proj -> wtp[n][k]
// ---------------------------------------------------------------------------
__global__ __launch_bounds__(256)
void prep_kernel(const float* __restrict__ Xs, const float* __restrict__ Xc,
                 const float* __restrict__ Ws, const float* __restrict__ Wc,
                 const float* __restrict__ Wp,
                 unsigned short* __restrict__ xb, unsigned short* __restrict__ wt,
                 unsigned short* __restrict__ wtp)
{
    const int bid = blockIdx.x, tid = threadIdx.x;
    if (bid < 2048) {
        int idx = bid * 2048 + tid * 8;
        const float* s = (idx < 2097152) ? (Xs + idx) : (Xc + idx - 2097152);
        f32x4 a0 = *(const f32x4*)s;
        f32x4 a1 = *(const f32x4*)(s + 4);
        bf16x8 v;
#pragma unroll
        for (int j = 0; j < 4; ++j) {
            ((unsigned short*)&v)[j]     = f2b(a0[j]);
            ((unsigned short*)&v)[4 + j] = f2b(a1[j]);
        }
        *(bf16x8*)(xb + idx) = v;
        return;
    }
    __shared__ unsigned short Tt[64 * 72];
    const float* W;
    unsigned short* dst;
    int k0, n0, ldn;
    float sc = 1.0f;
    if (bid < 2432) {
        int tj  = bid - 2048;
        int src = tj >= 192;  tj -= src * 192;
        k0  = (tj / 24) * 64;
        n0  = (tj % 24) * 64;
        W   = src ? Wc : Ws;
        ldn = 1536;
        dst = wt + (size_t)src * 786432;
        if (n0 < 512) sc = QSCALE;
    } else {
        int tj = bid - 2432;
        k0  = (tj >> 3) * 64;
        n0  = (tj & 7) * 64;
        W   = Wp;
        ldn = 512;
        dst = wtp;
    }
#pragma unroll
    for (int r = 0; r < 4; ++r) {
        int g  = tid + r * 256;
        int kr = g >> 4, nc4 = (g & 15) * 4;
        f32x4 v = *(const f32x4*)(W + (size_t)(k0 + kr) * ldn + n0 + nc4);
#pragma unroll
        for (int u = 0; u < 4; ++u)
            Tt[(nc4 + u) * 72 + kr] = f2b(v[u] * sc);
    }
    __syncthreads();
#pragma unroll
    for (int r = 0; r < 2; ++r) {
        int c = tid + r * 256;
        int nl = c >> 3, k8 = (c & 7) * 8;
        *(bf16x8*)(dst + (size_t)(n0 + nl) * 512 + k0 + k8) =
            *(const bf16x8*)(Tt + nl * 72 + k8);
    }
}

// ---------------------------------------------------------------------------
// QKV (swapped orientation): D[feature][token] = wt-rows . xb-rows^T + bias.
// 128(features) x 128(tokens) tile. NEW: double-buffered LDS (attn's verified
// orchestration): stage k-step s+1 while computing s; one barrier per step
// instead of two, and the glds drain overlaps compute. Staging/read formulas
// byte-identical to round-6/8 (buffer-indexed only). 2-bit XOR k-slot swizzle.
// ---------------------------------------------------------------------------
__global__ __launch_bounds__(256)
void qkv_kernel(const unsigned short* __restrict__ xb,
                const unsigned short* __restrict__ wt,
                const float* __restrict__ bs, const float* __restrict__ bc,
                unsigned short* __restrict__ qb, unsigned short* __restrict__ kb,
                unsigned short* __restrict__ vtb)
{
    const int src = blockIdx.z;
    const int m0 = blockIdx.y * 128;    // feature tile (12)
    const int n0 = blockIdx.x * 128;    // token tile (32)
    const float* bias = src ? bc : bs;
    const unsigned short* X = xb + (size_t)src * 2097152;
    const unsigned short* W = wt + (size_t)src * 786432;

    __shared__ unsigned short As[2][128 * 32];   // A = W (features), 8KB each
    __shared__ unsigned short Bs[2][128 * 32];   // B = X (tokens),   8KB each

    const int tid = threadIdx.x, lane = tid & 63, w = tid >> 6;
    const int quad = lane >> 4, r16 = lane & 15;
    const int mrow = (w >> 1) * 64, ncol = (w & 1) * 64;

    const f32x4 fz = {0.f, 0.f, 0.f, 0.f};
    f32x4 acc[4][4];
#pragma unroll
    for (int a = 0; a < 4; ++a)
#pragma unroll
        for (int b = 0; b < 4; ++b) acc[a][b] = fz;

    const int ci   = w << 1;
    const int rofs = lane >> 2;
    const int kswz = (((lane & 3) ^ ((lane >> 3) & 3))) * 8;
    const unsigned short* gA = W + (size_t)(m0 + ci * 16 + rofs) * 512 + kswz;
    const unsigned short* gB = X + (size_t)(n0 + ci * 16 + rofs) * 512 + kswz;
    const int lofs = ci * 512 + lane * 8;
    const int rsw = (r16 >> 1) & 3;           // read-side slot swizzle

#define QSTAGE(BB, K0) do {                                                    \
    glds16(gA + (K0), &As[BB][lofs]);                                          \
    glds16(gA + 16 * 512 + (K0), &As[BB][lofs + 512]);                         \
    glds16(gB + (K0), &Bs[BB][lofs]);                                          \
    glds16(gB + 16 * 512 + (K0), &Bs[BB][lofs + 512]);                         \
} while (0)

#define QCOMP(BB) do {                                                         \
    bf16x8 af[4], bfr[4];                                                      \
    _Pragma("unroll")                                                          \
    for (int ms = 0; ms < 4; ++ms)                                             \
        af[ms] = *(const bf16x8*)(&As[BB][(mrow + ms * 16 + r16) * 32          \
                                          + (quad ^ rsw) * 8]);                \
    _Pragma("unroll")                                                          \
    for (int ns = 0; ns < 4; ++ns)                                             \
        bfr[ns] = *(const bf16x8*)(&Bs[BB][(ncol + ns * 16 + r16) * 32         \
                                           + (quad ^ rsw) * 8]);               \
    _Pragma("unroll")                                                          \
    for (int ms = 0; ms < 4; ++ms)                                             \
        _Pragma("unroll")                                                      \
        for (int ns = 0; ns < 4; ++ns)                                         \
            acc[ms][ns] = __builtin_amdgcn_mfma_f32_16x16x32_bf16(             \
                af[ms], bfr[ns], acc[ms][ns], 0, 0, 0);                        \
} while (0)

    QSTAGE(0, 0);
    __syncthreads();                            // buf0 ready

    for (int k0 = 0; k0 < 512; k0 += 64) {
        QSTAGE(1, k0 + 32);                     // prefetch odd step
        QCOMP(0);
        __syncthreads();                        // odd staged; buf0 free
        if (k0 + 64 < 512) QSTAGE(0, k0 + 64);  // prefetch next even step
        QCOMP(1);
        __syncthreads();                        // even staged; buf1 free
    }

#undef QSTAGE
#undef QCOMP

    const int sec = m0 >> 9;    // 0=q,1=k,2=v (uniform per block)
#pragma unroll
    for (int ms = 0; ms < 4; ++ms) {
        const int f0 = m0 + mrow + ms * 16 + quad * 4;   // 4 consecutive feats
        const int hh = (f0 & 511) >> 6, j0 = f0 & 63;    // head, 4-aligned col
        f32x4 bb = *(const f32x4*)(bias + f0);
        if (sec == 0) bb = bb * QSCALE;
#pragma unroll
        for (int ns = 0; ns < 4; ++ns) {
            const int tcol = n0 + ncol + ns * 16 + r16;
            const int bi = tcol >> 10;
            const int tg = (tcol & 1023) + (src << 10);
            if (sec == 2) {                 // V: transposed + window-permuted
                const int r = tg & 31;
                const int pos = 2 * r - (r & 3) - ((r >> 4) * 28);
                const int tgp = (tg & ~31) + pos;
                unsigned short* vbase =
                    vtb + (((size_t)((bi * 8 + hh) * 64 + j0)) << 11) + tgp;
#pragma unroll
                for (int i = 0; i < 4; ++i)
                    vbase[(size_t)i << 11] = f2b(acc[ms][ns][i] + bb[i]);
            } else {
                unsigned short* dst = (sec == 0) ? qb : kb;
                bf16x4 pk;
#pragma unroll
                for (int i = 0; i < 4; ++i)
                    pk[i] = (short)f2b(acc[ms][ns][i] + bb[i]);
                *(bf16x4*)(dst + (((size_t)((bi * 8 + hh) * 2048 + tg)) << 6) + j0) = pk;
            }
        }
    }
}

// ---------------------------------------------------------------------------
// attn: round-8 verified kernel, byte-identical. S^T flash, exp2 domain,
// 4-buffer LDS pairing: 2 tiles staged + 2 computed per barrier interval
// (17 barriers). Block 256 thr = 4 waves; block = 128 queries (32/wave) of
// one bh. 64-key tiles, XOR swizzles both-sides, l via ones-A MFMA, direct
// write. Grid 512 = 32 bh x 16 qtiles, XCD-swizzled; LDS 72KB, 2 blocks/CU.
// ---------------------------------------------------------------------------

// stage K+V chunks j = w*2, w*2+1 of tile T into buffer BB
#define STAGE(BB, T) do {                                                      \
    _Pragma("unroll")                                                          \
    for (int r_ = 0; r_ < 2; ++r_) {                                           \
        const int j_ = (w << 1) + r_;                                          \
        const int row_ = (j_ << 3) + rofs;                                     \
        glds16(Kg + (size_t)(((T) << 6) + row_) * 64 + lsw,                    \
               &Kl[BB][(j_ << 9) + lane * 8]);                                 \
        glds16(Vg + (size_t)row_ * 2048 + ((T) << 6) + lsw,                    \
               &Vl[BB][(j_ << 9) + lane * 8]);                                 \
    }                                                                          \
} while (0)

#define DOG(G, TQ, PF) do {                                                    \
    f32x4 s0_ = fz, s1_ = fz;                                                  \
    __builtin_amdgcn_s_setprio(1);                                             \
    s0_ = __builtin_amdgcn_mfma_f32_16x16x32_bf16(ka00, qf[G][0], s0_, 0, 0, 0); \
    s0_ = __builtin_amdgcn_mfma_f32_16x16x32_bf16(ka01, qf[G][1], s0_, 0, 0, 0); \
    s1_ = __builtin_amdgcn_mfma_f32_16x16x32_bf16(ka10, qf[G][0], s1_, 0, 0, 0); \
    s1_ = __builtin_amdgcn_mfma_f32_16x16x32_bf16(ka11, qf[G][1], s1_, 0, 0, 0); \
    __builtin_amdgcn_s_setprio(0);                                             \
    float e_[8];                                                               \
    _Pragma("unroll")                                                          \
    for (int i_ = 0; i_ < 4; ++i_) {                                           \
        float a0_ = ((TQ) >= tk0[i_]) ? s0_[i_] : -1e9f;                       \
        float a1_ = ((TQ) >= tk1[i_]) ? s1_[i_] : -1e9f;                       \
        e_[i_]     = __builtin_amdgcn_exp2f(a0_);                              \
        e_[4 + i_] = __builtin_amdgcn_exp2f(a1_);                              \
    }                                                                          \
    union { unsigned int d[4]; bf16x8 v; } pu_;                                \
    pu_.d[0] = __builtin_amdgcn_perm(fbits(e_[1]), fbits(e_[0]), 0x07060302u); \
    pu_.d[1] = __builtin_amdgcn_perm(fbits(e_[3]), fbits(e_[2]), 0x07060302u); \
    pu_.d[2] = __builtin_amdgcn_perm(fbits(e_[5]), fbits(e_[4]), 0x07060302u); \
    pu_.d[3] = __builtin_amdgcn_perm(fbits(e_[7]), fbits(e_[6]), 0x07060302u); \
    PF = pu_.v;                                                                \
    al[G] = __builtin_amdgcn_mfma_f32_16x16x32_bf16(ones, PF, al[G], 0, 0, 0); \
} while (0)

// one 64-key tile T from buffer BB: two 32-key windows
#define DOTILE(BB, T) do {                                                     \
    const unsigned short* Kb_ = Kl[BB];                                        \
    const unsigned short* Vb_ = Vl[BB];                                        \
    _Pragma("unroll")                                                          \
    for (int c_ = 0; c_ < 2; ++c_) {                                           \
        bf16x8 ka00 = *(const bf16x8*)(Kb_ + (c_ * 32 + r16) * 64 + ((quad ^ rsx) << 3));        \
        bf16x8 ka01 = *(const bf16x8*)(Kb_ + (c_ * 32 + r16) * 64 + (((quad + 4) ^ rsx) << 3));  \
        bf16x8 ka10 = *(const bf16x8*)(Kb_ + (c_ * 32 + 16 + r16) * 64 + ((quad ^ rsx) << 3));   \
        bf16x8 ka11 = *(const bf16x8*)(Kb_ + (c_ * 32 + 16 + r16) * 64 + (((quad + 4) ^ rsx) << 3)); \
        i32x4 tk0 = *(const i32x4*)(Ts + ((T) << 6) + c_ * 32 + quad * 4);     \
        i32x4 tk1 = *(const i32x4*)(Ts + ((T) << 6) + c_ * 32 + 16 + quad * 4);\
        const int vs_ = ((4 * c_ + quad) ^ rsx) << 3;                          \
        bf16x8 va0 = *(const bf16x8*)(Vb_ + (r16) * 64 + vs_);                 \
        bf16x8 va1 = *(const bf16x8*)(Vb_ + (16 + r16) * 64 + vs_);            \
        bf16x8 va2 = *(const bf16x8*)(Vb_ + (32 + r16) * 64 + vs_);           \
        bf16x8 va3 = *(const bf16x8*)(Vb_ + (48 + r16) * 64 + vs_);            \
        bf16x8 pf0, pf1;                                                       \
        DOG(0, tq0, pf0);                                                      \
        DOG(1, tq1, pf1);                                                      \
        __builtin_amdgcn_s_setprio(1);                                         \
        ot[0][0] = __builtin_amdgcn_mfma_f32_16x16x32_bf16(va0, pf0, ot[0][0], 0, 0, 0); \
        ot[1][0] = __builtin_amdgcn_mfma_f32_16x16x32_bf16(va0, pf1, ot[1][0], 0, 0, 0); \
        ot[0][1] = __builtin_amdgcn_mfma_f32_16x16x32_bf16(va1, pf0, ot[0][1], 0, 0, 0); \
        ot[1][1] = __builtin_amdgcn_mfma_f32_16x16x32_bf16(va1, pf1, ot[1][1], 0, 0, 0); \
        ot[0][2] = __builtin_amdgcn_mfma_f32_16x16x32_bf16(va2, pf0, ot[0][2], 0, 0, 0); \
        ot[1][2] = __builtin_amdgcn_mfma_f32_16x16x32_bf16(va2, pf1, ot[1][2], 0, 0, 0); \
        ot[0][3] = __builtin_amdgcn_mfma_f32_16x16x32_bf16(va3, pf0, ot[0][3], 0, 0, 0); \
        ot[1][3] = __builtin_amdgcn_mfma_f32_16x16x32_bf16(va3, pf1, ot[1][3], 0, 0, 0); \
        __builtin_amdgcn_s_setprio(0);                                         \
    }                                                                          \
} while (0)

__global__ __launch_bounds__(256, 2)
void attn_kernel(const unsigned short* __restrict__ qb,
                 const unsigned short* __restrict__ kb,
                 const unsigned short* __restrict__ vt,
                 const int* __restrict__ t_self, const int* __restrict__ t_cross,
                 unsigned short* __restrict__ y)
{
    const int bid = blockIdx.x;
    const int bh = ((bid & 7) << 2) | ((bid >> 3) & 3);   // XCD-local bh group
    const int qt = bid >> 5;                              // 0..15, 128 q each
    const int b = bh >> 3, h = bh & 7;
    const int tid = threadIdx.x, w = tid >> 6, lane = tid & 63;
    const int quad = lane >> 4, r16 = lane & 15;
    const int rofs = lane >> 3;                 // staging row-within-chunk
    const int lsw  = ((lane & 7) ^ rofs) << 3;  // pre-swizzled source slot (shorts)
    const int rsx  = r16 & 7;                   // read-side swizzle term

    const unsigned short* Q  = qb + (size_t)bh * 131072;
    const unsigned short* Kg = kb + (size_t)bh * 131072;
    const unsigned short* Vg = vt + (size_t)bh * 131072;
    const int* tsb = t_self + b * 1024;
    const int* tcb = t_cross + b * 1024;

    __shared__ unsigned short Kl[4][4096];   // 8KB per buffer, swizzled
    __shared__ unsigned short Vl[4][4096];   // 8KB per buffer, swizzled
    __shared__ int Ts[2048];                 // all key times (absolute)

    // stage all key times once: 8 x glds16 (2 per wave)
#pragma unroll
    for (int r = 0; r < 2; ++r) {
        const int sg = (w << 1) + r;
        const int* src = (sg < 4) ? (tsb + sg * 256) : (tcb + (sg - 4) * 256);
        glds16i(src + lane * 4, Ts + sg * 256 + lane * 4);
    }

    const int q0w = qt * 128 + w * 32;          // this wave's 32 queries
    bf16x8 qf[2][2];
#pragma unroll
    for (int g = 0; g < 2; ++g)
#pragma unroll
        for (int ks = 0; ks < 2; ++ks)
            qf[g][ks] = *(const bf16x8*)(Q + (size_t)(q0w + g * 16 + r16) * 64
                                           + ks * 32 + quad * 8);
    const int* tqp = (q0w < 1024) ? (tsb + q0w) : (tcb + (q0w - 1024));
    const int tq0 = tqp[r16];
    const int tq1 = tqp[16 + r16];

    const f32x4 fz = {0.f, 0.f, 0.f, 0.f};
    f32x4 ot[2][4], al[2];
#pragma unroll
    for (int g = 0; g < 2; ++g) {
        al[g] = fz;
#pragma unroll
        for (int nt = 0; nt < 4; ++nt) ot[g][nt] = fz;
    }
    const bf16x8 ones = {(short)0x3F80, (short)0x3F80, (short)0x3F80, (short)0x3F80,
                         (short)0x3F80, (short)0x3F80, (short)0x3F80, (short)0x3F80};

    STAGE(0, 0);
    STAGE(1, 1);
    __syncthreads();                            // times + tiles 0,1 ready

    for (int T = 0; T < 32; T += 4) {
        STAGE(2, T + 2);                        // prefetch next pair
        STAGE(3, T + 3);
        DOTILE(0, T);
        DOTILE(1, T + 1);
        __syncthreads();                        // pair {2,3} staged; {0,1} free
        if (T + 4 < 32) {
            STAGE(0, T + 4);
            STAGE(1, T + 5);
        }
        DOTILE(2, T + 2);
        DOTILE(3, T + 3);
        __syncthreads();                        // pair {0,1} staged; {2,3} free
    }

    // epilogue: normalize and write y directly (no cross-wave merge)
#pragma unroll
    for (int g = 0; g < 2; ++g) {
        const float l = al[g][0];
        const float inv = (l > 0.f) ? (1.f / l) : 0.f;
        const size_t base = (((size_t)(b * 2048 + q0w + g * 16 + r16)) << 9) + h * 64;
#pragma unroll
        for (int nt = 0; nt < 4; ++nt) {
            bf16x4 pk;
#pragma unroll
            for (int i = 0; i < 4; ++i) pk[i] = (short)f2b(ot[g][nt][i] * inv);
            *(bf16x4*)(y + base + nt * 16 + quad * 4) = pk;
        }
    }
}

#undef STAGE
#undef DOG
#undef DOTILE

// ---------------------------------------------------------------------------
// proj (swapped orientation): D[feature][token] = wtp-rows . Y-rows^T + b.
// 64(features) x 128(tokens) tile -> grid 512. f32x4 stores, XOR k-slot
// swizzle. NEW: double-buffered LDS prefetch orchestration (24KB).
// ---------------------------------------------------------------------------
__global__ __launch_bounds__(256)
void proj_kernel(const unsigned short* __restrict__ X,
                 const unsigned short* __restrict__ Wt,
                 const float* __restrict__ bias,
                 float* __restrict__ out)
{
    const int m0 = blockIdx.y * 64;     // feature tile (8)
    const int n0 = blockIdx.x * 128;    // token tile (64)
    __shared__ unsigned short As[2][64 * 32];    // A = wtp (features), 4KB ea
    __shared__ unsigned short Bs[2][128 * 32];   // B = Y (tokens),     8KB ea

    const int tid = threadIdx.x, lane = tid & 63, w = tid >> 6;
    const int quad = lane >> 4, r16 = lane & 15;
    const int mrow = (w >> 1) * 32, ncol = (w & 1) * 64;

    const f32x4 fz = {0.f, 0.f, 0.f, 0.f};
    f32x4 acc[2][4];
#pragma unroll
    for (int a = 0; a < 2; ++a)
#pragma unroll
        for (int b = 0; b < 4; ++b) acc[a][b] = fz;

    const int rofs = lane >> 2;
    const int kswz = (((lane & 3) ^ ((lane >> 3) & 3))) * 8;
    const unsigned short* gA = Wt + (size_t)(m0 + w * 16 + rofs) * 512 + kswz;
    const unsigned short* gB = X + (size_t)(n0 + (w << 1) * 16 + rofs) * 512 + kswz;
    const int lofsA = w * 512 + lane * 8;
    const int lofsB = (w << 1) * 512 + lane * 8;
    const int rsw = (r16 >> 1) & 3;

#define PSTAGE(BB, K0) do {                                                    \
    glds16(gA + (K0), &As[BB][lofsA]);                                         \
    glds16(gB + (K0), &Bs[BB][lofsB]);                                         \
    glds16(gB + 16 * 512 + (K0), &Bs[BB][lofsB + 512]);                        \
} while (0)

#define PCOMP(BB) do {                                                         \
    bf16x8 af[2], bfr[4];                                                      \
    _Pragma("unroll")                                                          \
    for (int ms = 0; ms < 2; ++ms)                                             \
        af[ms] = *(const bf16x8*)(&As[BB][(mrow + ms * 16 + r16) * 32          \
                                          + (quad ^ rsw) * 8]);                \
    _Pragma("unroll")                                                          \
    for (int ns = 0; ns < 4; ++ns)                                             \
        bfr[ns] = *(const bf16x8*)(&Bs[BB][(ncol + ns * 16 + r16) * 32         \
                                           + (quad ^ rsw) * 8]);               \
    _Pragma("unroll")                                                          \
    for (int ms = 0; ms < 2; ++ms)                                             \
        _Pragma("unroll")                                                      \
        for (int ns = 0; ns < 4; ++ns)                                         \
            acc[ms][ns] = __builtin_amdgcn_mfma_f32_16x16x32_bf16(             \
                af[ms], bfr[ns], acc[ms][ns], 0, 0, 0);                        \
} while (0)

    PSTAGE(0, 0);
    __syncthreads();

    for (int k0 = 0; k0 < 512; k0 += 64) {
        PSTAGE(1, k0 + 32);
        PCOMP(0);
        __syncthreads();
        if (k0 + 64 < 512) PSTAGE(0, k0 + 64);
        PCOMP(1);
        __syncthreads();
    }

#undef PSTAGE
#undef PCOMP

#pragma unroll
    for (int ms = 0; ms < 2; ++ms) {
        const int f0 = m0 + mrow + ms * 16 + quad * 4;   // 4 consecutive feats
        f32x4 bb = *(const f32x4*)(bias + f0);
#pragma unroll
        for (int ns = 0; ns < 4; ++ns) {
            const int tok = n0 + ncol + ns * 16 + r16;
            const int bi = tok >> 11, t = tok & 2047;
            const size_t rowbase = (t < 1024)
                ? ((size_t)bi * 1024 + t) * 512
                : (size_t)2097152 + ((size_t)bi * 1024 + (t - 1024)) * 512;
            f32x4 v;
#pragma unroll
            for (int i = 0; i < 4; ++i) v[i] = acc[ms][ns][i] + bb[i];
            *(f32x4*)(out + rowbase + f0) = v;
        }
    }
}

// ---------------------------------------------------------------------------
extern "C" void kernel_launch(void* const* d_in, const int* in_sizes, int n_in,
                              void* d_out, int out_size, void* d_ws, size_t ws_size,
                              hipStream_t stream)
{
    const float* self_seq  = (const float*)d_in[0];
    const float* cross_seq = (const float*)d_in[1];
    const int*   t_self    = (const int*)d_in[2];
    const int*   t_cross   = (const int*)d_in[3];
    const float* W_self    = (const float*)d_in[4];
    const float* b_self    = (const float*)d_in[5];
    const float* W_cross   = (const float*)d_in[6];
    const float* b_cross   = (const float*)d_in[7];
    const float* W_proj    = (const float*)d_in[8];
    const float* b_proj    = (const float*)d_in[9];
    float* out = (float*)d_out;

    // ws (32 MB): q, k, vt, y (4 x 4,194,304 bf16).
    // d_out (33.5 MB fp32) slack holds xb (8 MB) + wt (3 MB) + wtp (0.5 MB)
    // as scratch until proj overwrites everything.
    unsigned short* qbuf = (unsigned short*)d_ws;
    unsigned short* kbuf = qbuf + 4194304;
    unsigned short* vtb  = kbuf + 4194304;
    unsigned short* ybuf = vtb + 4194304;
    unsigned short* xb   = (unsigned short*)d_out;
    unsigned short* wt   = xb + 4194304;
    unsigned short* wtp  = wt + 1572864;

    prep_kernel<<<dim3(2496), 256, 0, stream>>>(
        self_seq, cross_seq, W_self, W_cross, W_proj, xb, wt, wtp);

    qkv_kernel<<<dim3(32, 12, 2), 256, 0, stream>>>(
        xb, wt, b_self, b_cross, qbuf, kbuf, vtb);

    attn_kernel<<<dim3(512), 256, 0, stream>>>(
        qbuf, kbuf, vtb, t_self, t_cross, ybuf);

    proj_kernel<<<dim3(64, 8), 256, 0, stream>>>(
        ybuf, wtp, b_proj, out);
}

// Round 10
// 167.435 us; speedup vs baseline: 1.0521x; 1.0126x over previous
//
#include <hip/hip_runtime.h>

// ---------------------------------------------------------------------------
// SelfCrossAttention: B=4, T=1024+1024, d=512, H=8, hd=64. fp32 I/O,
// bf16 MFMA internals.
// prep (X->bf16; W_self/W_cross -> wt[n][k], q section pre-scaled by
//       0.125*log2(e) so attention runs in exp2 domain; W_proj -> wtp[n][k])
//   -> qkv (swapped-orientation 128x128 LDS GEMM, double-buffered prefetch,
//           XOR k-slot swizzle)
//   -> attn (round-8/9 verified structure; NEW: all s_setprio removed — the
//            12 setprio pairs/tile were compile-time scheduling fences that
//            prevented cross-window MFMA/VALU interleave (T5 is null-to-
//            negative for barrier-synced lockstep blocks, m190). Pure
//            deletion: no memory-semantics or formula change.)
//   -> proj (swapped orientation, 64x128 tile, double-buffered, f32x4
//            stores, XOR swizzle).
// ---------------------------------------------------------------------------

typedef short     bf16x8 __attribute__((ext_vector_type(8)));
typedef short     bf16x4 __attribute__((ext_vector_type(4)));
typedef float     f32x4  __attribute__((ext_vector_type(4)));
typedef int       i32x4  __attribute__((ext_vector_type(4)));

#define DI __device__ __forceinline__

DI unsigned short f2b(float f) {            // fp32 -> bf16 bits, RNE-ish
    union { float f; unsigned int u; } x; x.f = f;
    unsigned int r = x.u + 0x7fffu + ((x.u >> 16) & 1u);
    return (unsigned short)(r >> 16);
}
DI unsigned int fbits(float f) { union { float f; unsigned int u; } x; x.f = f; return x.u; }
DI float bitsf(unsigned int u) { union { unsigned int u; float f; } x; x.u = u; return x.f; }
DI float b2f(unsigned short v) { return bitsf(((unsigned int)v) << 16); }

DI void glds16(const unsigned short* g, unsigned short* l) {   // 16B global->LDS
    __builtin_amdgcn_global_load_lds(
        (const __attribute__((address_space(1))) void*)g,
        (__attribute__((address_space(3))) void*)l, 16, 0, 0);
}
DI void glds16i(const int* g, int* l) {
    __builtin_amdgcn_global_load_lds(
        (const __attribute__((address_space(1))) void*)g,
        (__attribute__((address_space(3))) void*)l, 16, 0, 0);
}

#define QSCALE 0.18033688011112042f   // 0.125 * log2(e): exp2-domain scores

// ---------------------------------------------------------------------------
// prep: [0,2048): X fp32 -> bf16 flat.
//       [2048,2432): W_self/W_cross -> wt[src][n][k], q-section * QSCALE
//       [2432,2496): W_proj -> wtp[n][k]
// ---------------------------------------------------------------------------
__global__ __launch_bounds__(256)
void prep_kernel(const float* __restrict__ Xs, const float* __restrict__ Xc,
                 const float* __restrict__ Ws, const float* __restrict__ Wc,
                 const float* __restrict__ Wp,
                 unsigned short* __restrict__ xb, unsigned short* __restrict__ wt,
                 unsigned short* __restrict__ wtp)
{
    const int bid = blockIdx.x, tid = threadIdx.x;
    if (bid < 2048) {
        int idx = bid * 2048 + tid * 8;
        const float* s = (idx < 2097152) ? (Xs + idx) : (Xc + idx - 2097152);
        f32x4 a0 = *(const f32x4*)s;
        f32x4 a1 = *(const f32x4*)(s + 4);
        bf16x8 v;
#pragma unroll
        for (int j = 0; j < 4; ++j) {
            ((unsigned short*)&v)[j]     = f2b(a0[j]);
            ((unsigned short*)&v)[4 + j] = f2b(a1[j]);
        }
        *(bf16x8*)(xb + idx) = v;
        return;
    }
    __shared__ unsigned short Tt[64 * 72];
    const float* W;
    unsigned short* dst;
    int k0, n0, ldn;
    float sc = 1.0f;
    if (bid < 2432) {
        int tj  = bid - 2048;
        int src = tj >= 192;  tj -= src * 192;
        k0  = (tj / 24) * 64;
        n0  = (tj % 24) * 64;
        W   = src ? Wc : Ws;
        ldn = 1536;
        dst = wt + (size_t)src * 786432;
        if (n0 < 512) sc = QSCALE;
    } else {
        int tj = bid - 2432;
        k0  = (tj >> 3) * 64;
        n0  = (tj & 7) * 64;
        W   = Wp;
        ldn = 512;
        dst = wtp;
    }
#pragma unroll
    for (int r = 0; r < 4; ++r) {
        int g  = tid + r * 256;
        int kr = g >> 4, nc4 = (g & 15) * 4;
        f32x4 v = *(const f32x4*)(W + (size_t)(k0 + kr) * ldn + n0 + nc4);
#pragma unroll
        for (int u = 0; u < 4; ++u)
            Tt[(nc4 + u) * 72 + kr] = f2b(v[u] * sc);
    }
    __syncthreads();
#pragma unroll
    for (int r = 0; r < 2; ++r) {
        int c = tid + r * 256;
        int nl = c >> 3, k8 = (c & 7) * 8;
        *(bf16x8*)(dst + (size_t)(n0 + nl) * 512 + k0 + k8) =
            *(const bf16x8*)(Tt + nl * 72 + k8);
    }
}

// ---------------------------------------------------------------------------
// QKV (swapped orientation): D[feature][token] = wt-rows . xb-rows^T + bias.
// 128(features) x 128(tokens) tile, double-buffered LDS prefetch, 2-bit XOR
// k-slot swizzle both-sides.
// ---------------------------------------------------------------------------
__global__ __launch_bounds__(256)
void qkv_kernel(const unsigned short* __restrict__ xb,
                const unsigned short* __restrict__ wt,
                const float* __restrict__ bs, const float* __restrict__ bc,
                unsigned short* __restrict__ qb, unsigned short* __restrict__ kb,
                unsigned short* __restrict__ vtb)
{
    const int src = blockIdx.z;
    const int m0 = blockIdx.y * 128;    // feature tile (12)
    const int n0 = blockIdx.x * 128;    // token tile (32)
    const float* bias = src ? bc : bs;
    const unsigned short* X = xb + (size_t)src * 2097152;
    const unsigned short* W = wt + (size_t)src * 786432;

    __shared__ unsigned short As[2][128 * 32];   // A = W (features), 8KB each
    __shared__ unsigned short Bs[2][128 * 32];   // B = X (tokens),   8KB each

    const int tid = threadIdx.x, lane = tid & 63, w = tid >> 6;
    const int quad = lane >> 4, r16 = lane & 15;
    const int mrow = (w >> 1) * 64, ncol = (w & 1) * 64;

    const f32x4 fz = {0.f, 0.f, 0.f, 0.f};
    f32x4 acc[4][4];
#pragma unroll
    for (int a = 0; a < 4; ++a)
#pragma unroll
        for (int b = 0; b < 4; ++b) acc[a][b] = fz;

    const int ci   = w << 1;
    const int rofs = lane >> 2;
    const int kswz = (((lane & 3) ^ ((lane >> 3) & 3))) * 8;
    const unsigned short* gA = W + (size_t)(m0 + ci * 16 + rofs) * 512 + kswz;
    const unsigned short* gB = X + (size_t)(n0 + ci * 16 + rofs) * 512 + kswz;
    const int lofs = ci * 512 + lane * 8;
    const int rsw = (r16 >> 1) & 3;           // read-side slot swizzle

#define QSTAGE(BB, K0) do {                                                    \
    glds16(gA + (K0), &As[BB][lofs]);                                          \
    glds16(gA + 16 * 512 + (K0), &As[BB][lofs + 512]);                         \
    glds16(gB + (K0), &Bs[BB][lofs]);                                          \
    glds16(gB + 16 * 512 + (K0), &Bs[BB][lofs + 512]);                         \
} while (0)

#define QCOMP(BB) do {                                                         \
    bf16x8 af[4], bfr[4];                                                      \
    _Pragma("unroll")                                                          \
    for (int ms = 0; ms < 4; ++ms)                                             \
        af[ms] = *(const bf16x8*)(&As[BB][(mrow + ms * 16 + r16) * 32          \
                                          + (quad ^ rsw) * 8]);                \
    _Pragma("unroll")                                                          \
    for (int ns = 0; ns < 4; ++ns)                                             \
        bfr[ns] = *(const bf16x8*)(&Bs[BB][(ncol + ns * 16 + r16) * 32         \
                                           + (quad ^ rsw) * 8]);               \
    _Pragma("unroll")                                                          \
    for (int ms = 0; ms < 4; ++ms)                                             \
        _Pragma("unroll")                                                      \
        for (int ns = 0; ns < 4; ++ns)                                         \
            acc[ms][ns] = __builtin_amdgcn_mfma_f32_16x16x32_bf16(             \
                af[ms], bfr[ns], acc[ms][ns], 0, 0, 0);                        \
} while (0)

    QSTAGE(0, 0);
    __syncthreads();                            // buf0 ready

    for (int k0 = 0; k0 < 512; k0 += 64) {
        QSTAGE(1, k0 + 32);                     // prefetch odd step
        QCOMP(0);
        __syncthreads();                        // odd staged; buf0 free
        if (k0 + 64 < 512) QSTAGE(0, k0 + 64);  // prefetch next even step
        QCOMP(1);
        __syncthreads();                        // even staged; buf1 free
    }

#undef QSTAGE
#undef QCOMP

    const int sec = m0 >> 9;    // 0=q,1=k,2=v (uniform per block)
#pragma unroll
    for (int ms = 0; ms < 4; ++ms) {
        const int f0 = m0 + mrow + ms * 16 + quad * 4;   // 4 consecutive feats
        const int hh = (f0 & 511) >> 6, j0 = f0 & 63;    // head, 4-aligned col
        f32x4 bb = *(const f32x4*)(bias + f0);
        if (sec == 0) bb = bb * QSCALE;
#pragma unroll
        for (int ns = 0; ns < 4; ++ns) {
            const int tcol = n0 + ncol + ns * 16 + r16;
            const int bi = tcol >> 10;
            const int tg = (tcol & 1023) + (src << 10);
            if (sec == 2) {                 // V: transposed + window-permuted
                const int r = tg & 31;
                const int pos = 2 * r - (r & 3) - ((r >> 4) * 28);
                const int tgp = (tg & ~31) + pos;
                unsigned short* vbase =
                    vtb + (((size_t)((bi * 8 + hh) * 64 + j0)) << 11) + tgp;
#pragma unroll
                for (int i = 0; i < 4; ++i)
                    vbase[(size_t)i << 11] = f2b(acc[ms][ns][i] + bb[i]);
            } else {
                unsigned short* dst = (sec == 0) ? qb : kb;
                bf16x4 pk;
#pragma unroll
                for (int i = 0; i < 4; ++i)
                    pk[i] = (short)f2b(acc[ms][ns][i] + bb[i]);
                *(bf16x4*)(dst + (((size_t)((bi * 8 + hh) * 2048 + tg)) << 6) + j0) = pk;
            }
        }
    }
}

// ---------------------------------------------------------------------------
// attn: S^T flash, exp2 domain. Round-8/9 verified structure (4-buffer
// pairing, 17 barriers, 64-key tiles, XOR swizzles both-sides, l via ones-A
// MFMA, direct write) with ALL s_setprio REMOVED: the setprio intrinsics are
// side-effecting and acted as 12 scheduling fences per tile, preventing the
// compiler from interleaving window c+1's independent QK MFMAs / ds_reads
// into window c's exp2/pack VALU shadow. Pure deletion — no memory-semantics
// change. Block 256 thr = 4 waves; 128 q/block of one bh; grid 512, 72KB LDS.
// ---------------------------------------------------------------------------

// stage K+V chunks j = w*2, w*2+1 of tile T into buffer BB
#define STAGE(BB, T) do {                                                      \
    _Pragma("unroll")                                                          \
    for (int r_ = 0; r_ < 2; ++r_) {                                           \
        const int j_ = (w << 1) + r_;                                          \
        const int row_ = (j_ << 3) + rofs;                                     \
        glds16(Kg + (size_t)(((T) << 6) + row_) * 64 + lsw,                    \
               &Kl[BB][(j_ << 9) + lane * 8]);                                 \
        glds16(Vg + (size_t)row_ * 2048 + ((T) << 6) + lsw,                    \
               &Vl[BB][(j_ << 9) + lane * 8]);                                 \
    }                                                                          \
} while (0)

#define DOG(G, TQ, PF) do {                                                    \
    f32x4 s0_ = fz, s1_ = fz;                                                  \
    s0_ = __builtin_amdgcn_mfma_f32_16x16x32_bf16(ka00, qf[G][0], s0_, 0, 0, 0); \
    s0_ = __builtin_amdgcn_mfma_f32_16x16x32_bf16(ka01, qf[G][1], s0_, 0, 0, 0); \
    s1_ = __builtin_amdgcn_mfma_f32_16x16x32_bf16(ka10, qf[G][0], s1_, 0, 0, 0); \
    s1_ = __builtin_amdgcn_mfma_f32_16x16x32_bf16(ka11, qf[G][1], s1_, 0, 0, 0); \
    float e_[8];                                                               \
    _Pragma("unroll")                                                          \
    for (int i_ = 0; i_ < 4; ++i_) {                                           \
        float a0_ = ((TQ) >= tk0[i_]) ? s0_[i_] : -1e9f;                       \
        float a1_ = ((TQ) >= tk1[i_]) ? s1_[i_] : -1e9f;                       \
        e_[i_]     = __builtin_amdgcn_exp2f(a0_);                              \
        e_[4 + i_] = __builtin_amdgcn_exp2f(a1_);                              \
    }                                                                          \
    union { unsigned int d[4]; bf16x8 v; } pu_;                                \
    pu_.d[0] = __builtin_amdgcn_perm(fbits(e_[1]), fbits(e_[0]), 0x07060302u); \
    pu_.d[1] = __builtin_amdgcn_perm(fbits(e_[3]), fbits(e_[2]), 0x07060302u); \
    pu_.d[2] = __builtin_amdgcn_perm(fbits(e_[5]), fbits(e_[4]), 0x07060302u); \
    pu_.d[3] = __builtin_amdgcn_perm(fbits(e_[7]), fbits(e_[6]), 0x07060302u); \
    PF = pu_.v;                                                                \
    al[G] = __builtin_amdgcn_mfma_f32_16x16x32_bf16(ones, PF, al[G], 0, 0, 0); \
} while (0)

// one 64-key tile T from buffer BB: two 32-key windows
#define DOTILE(BB, T) do {                                                     \
    const unsigned short* Kb_ = Kl[BB];                                        \
    const unsigned short* Vb_ = Vl[BB];                                        \
    _Pragma("unroll")                                                          \
    for (int c_ = 0; c_ < 2; ++c_) {                                           \
        bf16x8 ka00 = *(const bf16x8*)(Kb_ + (c_ * 32 + r16) * 64 + ((quad ^ rsx) << 3));        \
        bf16x8 ka01 = *(const bf16x8*)(Kb_ + (c_ * 32 + r16) * 64 + (((quad + 4) ^ rsx) << 3));  \
        bf16x8 ka10 = *(const bf16x8*)(Kb_ + (c_ * 32 + 16 + r16) * 64 + ((quad ^ rsx) << 3));   \
        bf16x8 ka11 = *(const bf16x8*)(Kb_ + (c_ * 32 + 16 + r16) * 64 + (((quad + 4) ^ rsx) << 3)); \
        i32x4 tk0 = *(const i32x4*)(Ts + ((T) << 6) + c_ * 32 + quad * 4);     \
        i32x4 tk1 = *(const i32x4*)(Ts + ((T) << 6) + c_ * 32 + 16 + quad * 4);\
        const int vs_ = ((4 * c_ + quad) ^ rsx) << 3;                          \
        bf16x8 va0 = *(const bf16x8*)(Vb_ + (r16) * 64 + vs_);                 \
        bf16x8 va1 = *(const bf16x8*)(Vb_ + (16 + r16) * 64 + vs_);            \
        bf16x8 va2 = *(const bf16x8*)(Vb_ + (32 + r16) * 64 + vs_);            \
        bf16x8 va3 = *(const bf16x8*)(Vb_ + (48 + r16) * 64 + vs_);            \
        bf16x8 pf0, pf1;                                                       \
        DOG(0, tq0, pf0);                                                      \
        DOG(1, tq1, pf1);                                                      \
        ot[0][0] = __builtin_amdgcn_mfma_f32_16x16x32_bf16(va0, pf0, ot[0][0], 0, 0, 0); \
        ot[1][0] = __builtin_amdgcn_mfma_f32_16x16x32_bf16(va0, pf1, ot[1][0], 0, 0, 0); \
        ot[0][1] = __builtin_amdgcn_mfma_f32_16x16x32_bf16(va1, pf0, ot[0][1], 0, 0, 0); \
        ot[1][1] = __builtin_amdgcn_mfma_f32_16x16x32_bf16(va1, pf1, ot[1][1], 0, 0, 0); \
        ot[0][2] = __builtin_amdgcn_mfma_f32_16x16x32_bf16(va2, pf0, ot[0][2], 0, 0, 0); \
        ot[1][2] = __builtin_amdgcn_mfma_f32_16x16x32_bf16(va2, pf1, ot[1][2], 0, 0, 0); \
        ot[0][3] = __builtin_amdgcn_mfma_f32_16x16x32_bf16(va3, pf0, ot[0][3], 0, 0, 0); \
        ot[1][3] = __builtin_amdgcn_mfma_f32_16x16x32_bf16(va3, pf1, ot[1][3], 0, 0, 0); \
    }                                                                          \
} while (0)

__global__ __launch_bounds__(256, 2)
void attn_kernel(const unsigned short* __restrict__ qb,
                 const unsigned short* __restrict__ kb,
                 const unsigned short* __restrict__ vt,
                 const int* __restrict__ t_self, const int* __restrict__ t_cross,
                 unsigned short* __restrict__ y)
{
    const int bid = blockIdx.x;
    const int bh = ((bid & 7) << 2) | ((bid >> 3) & 3);   // XCD-local bh group
    const int qt = bid >> 5;                              // 0..15, 128 q each
    const int b = bh >> 3, h = bh & 7;
    const int tid = threadIdx.x, w = tid >> 6, lane = tid & 63;
    const int quad = lane >> 4, r16 = lane & 15;
    const int rofs = lane >> 3;                 // staging row-within-chunk
    const int lsw  = ((lane & 7) ^ rofs) << 3;  // pre-swizzled source slot (shorts)
    const int rsx  = r16 & 7;                   // read-side swizzle term

    const unsigned short* Q  = qb + (size_t)bh * 131072;
    const unsigned short* Kg = kb + (size_t)bh * 131072;
    const unsigned short* Vg = vt + (size_t)bh * 131072;
    const int* tsb = t_self + b * 1024;
    const int* tcb = t_cross + b * 1024;

    __shared__ unsigned short Kl[4][4096];   // 8KB per buffer, swizzled
    __shared__ unsigned short Vl[4][4096];   // 8KB per buffer, swizzled
    __shared__ int Ts[2048];                 // all key times (absolute)

    // stage all key times once: 8 x glds16 (2 per wave)
#pragma unroll
    for (int r = 0; r < 2; ++r) {
        const int sg = (w << 1) + r;
        const int* src = (sg < 4) ? (tsb + sg * 256) : (tcb + (sg - 4) * 256);
        glds16i(src + lane * 4, Ts + sg * 256 + lane * 4);
    }

    const int q0w = qt * 128 + w * 32;          // this wave's 32 queries
    bf16x8 qf[2][2];
#pragma unroll
    for (int g = 0; g < 2; ++g)
#pragma unroll
        for (int ks = 0; ks < 2; ++ks)
            qf[g][ks] = *(const bf16x8*)(Q + (size_t)(q0w + g * 16 + r16) * 64
                                           + ks * 32 + quad * 8);
    const int* tqp = (q0w < 1024) ? (tsb + q0w) : (tcb + (q0w - 1024));
    const int tq0 = tqp[r16];
    const int tq1 = tqp[16 + r16];

    const f32x4 fz = {0.f, 0.f, 0.f, 0.f};
    f32x4 ot[2][4], al[2];
#pragma unroll
    for (int g = 0; g < 2; ++g) {
        al[g] = fz;
#pragma unroll
        for (int nt = 0; nt < 4; ++nt) ot[g][nt] = fz;
    }
    const bf16x8 ones = {(short)0x3F80, (short)0x3F80, (short)0x3F80, (short)0x3F80,
                         (short)0x3F80, (short)0x3F80, (short)0x3F80, (short)0x3F80};

    STAGE(0, 0);
    STAGE(1, 1);
    __syncthreads();                            // times + tiles 0,1 ready

    for (int T = 0; T < 32; T += 4) {
        STAGE(2, T + 2);                        // prefetch next pair
        STAGE(3, T + 3);
        DOTILE(0, T);
        DOTILE(1, T + 1);
        __syncthreads();                        // pair {2,3} staged; {0,1} free
        if (T + 4 < 32) {
            STAGE(0, T + 4);
            STAGE(1, T + 5);
        }
        DOTILE(2, T + 2);
        DOTILE(3, T + 3);
        __syncthreads();                        // pair {0,1} staged; {2,3} free
    }

    // epilogue: normalize and write y directly (no cross-wave merge)
#pragma unroll
    for (int g = 0; g < 2; ++g) {
        const float l = al[g][0];
        const float inv = (l > 0.f) ? (1.f / l) : 0.f;
        const size_t base = (((size_t)(b * 2048 + q0w + g * 16 + r16)) << 9) + h * 64;
#pragma unroll
        for (int nt = 0; nt < 4; ++nt) {
            bf16x4 pk;
#pragma unroll
            for (int i = 0; i < 4; ++i) pk[i] = (short)f2b(ot[g][nt][i] * inv);
            *(bf16x4*)(y + base + nt * 16 + quad * 4) = pk;
        }
    }
}

#undef STAGE
#undef DOG
#undef DOTILE

// ---------------------------------------------------------------------------
// proj (swapped orientation): D[feature][token] = wtp-rows . Y-rows^T + b.
// 64(features) x 128(tokens) tile -> grid 512. f32x4 stores, XOR k-slot
// swizzle, double-buffered LDS prefetch (24KB).
// ---------------------------------------------------------------------------
__global__ __launch_bounds__(256)
void proj_kernel(const unsigned short* __restrict__ X,
                 const unsigned short* __restrict__ Wt,
                 const float* __restrict__ bias,
                 float* __restrict__ out)
{
    const int m0 = blockIdx.y * 64;     // feature tile (8)
    const int n0 = blockIdx.x * 128;    // token tile (64)
    __shared__ unsigned short As[2][64 * 32];    // A = wtp (features), 4KB ea
    __shared__ unsigned short Bs[2][128 * 32];   // B = Y (tokens),     8KB ea

    const int tid = threadIdx.x, lane = tid & 63, w = tid >> 6;
    const int quad = lane >> 4, r16 = lane & 15;
    const int mrow = (w >> 1) * 32, ncol = (w & 1) * 64;

    const f32x4 fz = {0.f, 0.f, 0.f, 0.f};
    f32x4 acc[2][4];
#pragma unroll
    for (int a = 0; a < 2; ++a)
#pragma unroll
        for (int b = 0; b < 4; ++b) acc[a][b] = fz;

    const int rofs = lane >> 2;
    const int kswz = (((lane & 3) ^ ((lane >> 3) & 3))) * 8;
    const unsigned short* gA = Wt + (size_t)(m0 + w * 16 + rofs) * 512 + kswz;
    const unsigned short* gB = X + (size_t)(n0 + (w << 1) * 16 + rofs) * 512 + kswz;
    const int lofsA = w * 512 + lane * 8;
    const int lofsB = (w << 1) * 512 + lane * 8;
    const int rsw = (r16 >> 1) & 3;

#define PSTAGE(BB, K0) do {                                                    \
    glds16(gA + (K0), &As[BB][lofsA]);                                         \
    glds16(gB + (K0), &Bs[BB][lofsB]);                                         \
    glds16(gB + 16 * 512 + (K0), &Bs[BB][lofsB + 512]);                        \
} while (0)

#define PCOMP(BB) do {                                                         \
    bf16x8 af[2], bfr[4];                                                      \
    _Pragma("unroll")                                                          \
    for (int ms = 0; ms < 2; ++ms)                                             \
        af[ms] = *(const bf16x8*)(&As[BB][(mrow + ms * 16 + r16) * 32          \
                                          + (quad ^ rsw) * 8]);                \
    _Pragma("unroll")                                                          \
    for (int ns = 0; ns < 4; ++ns)                                             \
        bfr[ns] = *(const bf16x8*)(&Bs[BB][(ncol + ns * 16 + r16) * 32         \
                                           + (quad ^ rsw) * 8]);               \
    _Pragma("unroll")                                                          \
    for (int ms = 0; ms < 2; ++ms)                                             \
        _Pragma("unroll")                                                      \
        for (int ns = 0; ns < 4; ++ns)                                         \
            acc[ms][ns] = __builtin_amdgcn_mfma_f32_16x16x32_bf16(             \
                af[ms], bfr[ns], acc[ms][ns], 0, 0, 0);                        \
} while (0)

    PSTAGE(0, 0);
    __syncthreads();

    for (int k0 = 0; k0 < 512; k0 += 64) {
        PSTAGE(1, k0 + 32);
        PCOMP(0);
        __syncthreads();
        if (k0 + 64 < 512) PSTAGE(0, k0 + 64);
        PCOMP(1);
        __syncthreads();
    }

#undef PSTAGE
#undef PCOMP

#pragma unroll
    for (int ms = 0; ms < 2; ++ms) {
        const int f0 = m0 + mrow + ms * 16 + quad * 4;   // 4 consecutive feats
        f32x4 bb = *(const f32x4*)(bias + f0);
#pragma unroll
        for (int ns = 0; ns < 4; ++ns) {
            const int tok = n0 + ncol + ns * 16 + r16;
            const int bi = tok >> 11, t = tok & 2047;
            const size_t rowbase = (t < 1024)
                ? ((size_t)bi * 1024 + t) * 512
                : (size_t)2097152 + ((size_t)bi * 1024 + (t - 1024)) * 512;
            f32x4 v;
#pragma unroll
            for (int i = 0; i < 4; ++i) v[i] = acc[ms][ns][i] + bb[i];
            *(f32x4*)(out + rowbase + f0) = v;
        }
    }
}

// ---------------------------------------------------------------------------
extern "C" void kernel_launch(void* const* d_in, const int* in_sizes, int n_in,
                              void* d_out, int out_size, void* d_ws, size_t ws_size,
                              hipStream_t stream)
{
    const float* self_seq  = (const float*)d_in[0];
    const float* cross_seq = (const float*)d_in[1];
    const int*   t_self    = (const int*)d_in[2];
    const int*   t_cross   = (const int*)d_in[3];
    const float* W_self    = (const float*)d_in[4];
    const float* b_self    = (const float*)d_in[5];
    const float* W_cross   = (const float*)d_in[6];
    const float* b_cross   = (const float*)d_in[7];
    const float* W_proj    = (const float*)d_in[8];
    const float* b_proj    = (const float*)d_in[9];
    float* out = (float*)d_out;

    // ws (32 MB): q, k, vt, y (4 x 4,194,304 bf16).
    // d_out (33.5 MB fp32) slack holds xb (8 MB) + wt (3 MB) + wtp (0.5 MB)
    // as scratch until proj overwrites everything.
    unsigned short* qbuf = (unsigned short*)d_ws;
    unsigned short* kbuf = qbuf + 4194304;
    unsigned short* vtb  = kbuf + 4194304;
    unsigned short* ybuf = vtb + 4194304;
    unsigned short* xb   = (unsigned short*)d_out;
    unsigned short* wt   = xb + 4194304;
    unsigned short* wtp  = wt + 1572864;

    prep_kernel<<<dim3(2496), 256, 0, stream>>>(
        self_seq, cross_seq, W_self, W_cross, W_proj, xb, wt, wtp);

    qkv_kernel<<<dim3(32, 12, 2), 256, 0, stream>>>(
        xb, wt, b_self, b_cross, qbuf, kbuf, vtb);

    attn_kernel<<<dim3(512), 256, 0, stream>>>(
        qbuf, kbuf, vtb, t_self, t_cross, ybuf);

    proj_kernel<<<dim3(64, 8), 256, 0, stream>>>(
        ybuf, wtp, b_proj, out);
}

// Round 11
// 167.055 us; speedup vs baseline: 1.0545x; 1.0023x over previous
//
#include <hip/hip_runtime.h>

// ---------------------------------------------------------------------------
// SelfCrossAttention: B=4, T=1024+1024, d=512, H=8, hd=64. fp32 I/O,
// bf16 MFMA internals.  (Round-9 configuration — best verified.)
// prep (X->bf16; W_self/W_cross -> wt[n][k], q section pre-scaled by
//       0.125*log2(e) so attention runs in exp2 domain; W_proj -> wtp[n][k])
//   -> qkv (swapped-orientation 128x128 LDS GEMM, double-buffered prefetch,
//           XOR k-slot swizzle)
//   -> attn (5x-verified: 4-buffer pairing, 2 tiles staged + 2 computed per
//            barrier interval (17 barriers), 64-key tiles, XOR swizzles
//            both-sides, s_setprio around MFMA clusters (measured +4% here:
//            round-10 removal cost 2us — this structure is in setprio's
//            "pays" regime despite barrier sync), exp2 softmax, l via
//            ones-A MFMA, direct write. 72KB LDS, 2 blocks/CU.)
//   -> proj (swapped orientation, 64x128 tile, double-buffered, f32x4
//            stores, XOR swizzle).
// ---------------------------------------------------------------------------

typedef short     bf16x8 __attribute__((ext_vector_type(8)));
typedef short     bf16x4 __attribute__((ext_vector_type(4)));
typedef float     f32x4  __attribute__((ext_vector_type(4)));
typedef int       i32x4  __attribute__((ext_vector_type(4)));

#define DI __device__ __forceinline__

DI unsigned short f2b(float f) {            // fp32 -> bf16 bits, RNE-ish
    union { float f; unsigned int u; } x; x.f = f;
    unsigned int r = x.u + 0x7fffu + ((x.u >> 16) & 1u);
    return (unsigned short)(r >> 16);
}
DI unsigned int fbits(float f) { union { float f; unsigned int u; } x; x.f = f; return x.u; }
DI float bitsf(unsigned int u) { union { unsigned int u; float f; } x; x.u = u; return x.f; }
DI float b2f(unsigned short v) { return bitsf(((unsigned int)v) << 16); }

DI void glds16(const unsigned short* g, unsigned short* l) {   // 16B global->LDS
    __builtin_amdgcn_global_load_lds(
        (const __attribute__((address_space(1))) void*)g,
        (__attribute__((address_space(3))) void*)l, 16, 0, 0);
}
DI void glds16i(const int* g, int* l) {
    __builtin_amdgcn_global_load_lds(
        (const __attribute__((address_space(1))) void*)g,
        (__attribute__((address_space(3))) void*)l, 16, 0, 0);
}

#define QSCALE 0.18033688011112042f   // 0.125 * log2(e): exp2-domain scores

// ---------------------------------------------------------------------------
// prep: [0,2048): X fp32 -> bf16 flat.
//       [2048,2432): W_self/W_cross -> wt[src][n][k], q-section * QSCALE
//       [2432,2496): W_proj -> wtp[n][k]
// ---------------------------------------------------------------------------
__global__ __launch_bounds__(256)
void prep_kernel(const float* __restrict__ Xs, const float* __restrict__ Xc,
                 const float* __restrict__ Ws, const float* __restrict__ Wc,
                 const float* __restrict__ Wp,
                 unsigned short* __restrict__ xb, unsigned short* __restrict__ wt,
                 unsigned short* __restrict__ wtp)
{
    const int bid = blockIdx.x, tid = threadIdx.x;
    if (bid < 2048) {
        int idx = bid * 2048 + tid * 8;
        const float* s = (idx < 2097152) ? (Xs + idx) : (Xc + idx - 2097152);
        f32x4 a0 = *(const f32x4*)s;
        f32x4 a1 = *(const f32x4*)(s + 4);
        bf16x8 v;
#pragma unroll
        for (int j = 0; j < 4; ++j) {
            ((unsigned short*)&v)[j]     = f2b(a0[j]);
            ((unsigned short*)&v)[4 + j] = f2b(a1[j]);
        }
        *(bf16x8*)(xb + idx) = v;
        return;
    }
    __shared__ unsigned short Tt[64 * 72];
    const float* W;
    unsigned short* dst;
    int k0, n0, ldn;
    float sc = 1.0f;
    if (bid < 2432) {
        int tj  = bid - 2048;
        int src = tj >= 192;  tj -= src * 192;
        k0  = (tj / 24) * 64;
        n0  = (tj % 24) * 64;
        W   = src ? Wc : Ws;
        ldn = 1536;
        dst = wt + (size_t)src * 786432;
        if (n0 < 512) sc = QSCALE;
    } else {
        int tj = bid - 2432;
        k0  = (tj >> 3) * 64;
        n0  = (tj & 7) * 64;
        W   = Wp;
        ldn = 512;
        dst = wtp;
    }
#pragma unroll
    for (int r = 0; r < 4; ++r) {
        int g  = tid + r * 256;
        int kr = g >> 4, nc4 = (g & 15) * 4;
        f32x4 v = *(const f32x4*)(W + (size_t)(k0 + kr) * ldn + n0 + nc4);
#pragma unroll
        for (int u = 0; u < 4; ++u)
            Tt[(nc4 + u) * 72 + kr] = f2b(v[u] * sc);
    }
    __syncthreads();
#pragma unroll
    for (int r = 0; r < 2; ++r) {
        int c = tid + r * 256;
        int nl = c >> 3, k8 = (c & 7) * 8;
        *(bf16x8*)(dst + (size_t)(n0 + nl) * 512 + k0 + k8) =
            *(const bf16x8*)(Tt + nl * 72 + k8);
    }
}

// ---------------------------------------------------------------------------
// QKV (swapped orientation): D[feature][token] = wt-rows . xb-rows^T + bias.
// 128(features) x 128(tokens) tile, double-buffered LDS prefetch, 2-bit XOR
// k-slot swizzle both-sides.
// ---------------------------------------------------------------------------
__global__ __launch_bounds__(256)
void qkv_kernel(const unsigned short* __restrict__ xb,
                const unsigned short* __restrict__ wt,
                const float* __restrict__ bs, const float* __restrict__ bc,
                unsigned short* __restrict__ qb, unsigned short* __restrict__ kb,
                unsigned short* __restrict__ vtb)
{
    const int src = blockIdx.z;
    const int m0 = blockIdx.y * 128;    // feature tile (12)
    const int n0 = blockIdx.x * 128;    // token tile (32)
    const float* bias = src ? bc : bs;
    const unsigned short* X = xb + (size_t)src * 2097152;
    const unsigned short* W = wt + (size_t)src * 786432;

    __shared__ unsigned short As[2][128 * 32];   // A = W (features), 8KB each
    __shared__ unsigned short Bs[2][128 * 32];   // B = X (tokens),   8KB each

    const int tid = threadIdx.x, lane = tid & 63, w = tid >> 6;
    const int quad = lane >> 4, r16 = lane & 15;
    const int mrow = (w >> 1) * 64, ncol = (w & 1) * 64;

    const f32x4 fz = {0.f, 0.f, 0.f, 0.f};
    f32x4 acc[4][4];
#pragma unroll
    for (int a = 0; a < 4; ++a)
#pragma unroll
        for (int b = 0; b < 4; ++b) acc[a][b] = fz;

    const int ci   = w << 1;
    const int rofs = lane >> 2;
    const int kswz = (((lane & 3) ^ ((lane >> 3) & 3))) * 8;
    const unsigned short* gA = W + (size_t)(m0 + ci * 16 + rofs) * 512 + kswz;
    const unsigned short* gB = X + (size_t)(n0 + ci * 16 + rofs) * 512 + kswz;
    const int lofs = ci * 512 + lane * 8;
    const int rsw = (r16 >> 1) & 3;           // read-side slot swizzle

#define QSTAGE(BB, K0) do {                                                    \
    glds16(gA + (K0), &As[BB][lofs]);                                          \
    glds16(gA + 16 * 512 + (K0), &As[BB][lofs + 512]);                         \
    glds16(gB + (K0), &Bs[BB][lofs]);                                          \
    glds16(gB + 16 * 512 + (K0), &Bs[BB][lofs + 512]);                         \
} while (0)

#define QCOMP(BB) do {                                                         \
    bf16x8 af[4], bfr[4];                                                      \
    _Pragma("unroll")                                                          \
    for (int ms = 0; ms < 4; ++ms)                                             \
        af[ms] = *(const bf16x8*)(&As[BB][(mrow + ms * 16 + r16) * 32          \
                                          + (quad ^ rsw) * 8]);                \
    _Pragma("unroll")                                                          \
    for (int ns = 0; ns < 4; ++ns)                                             \
        bfr[ns] = *(const bf16x8*)(&Bs[BB][(ncol + ns * 16 + r16) * 32         \
                                           + (quad ^ rsw) * 8]);               \
    _Pragma("unroll")                                                          \
    for (int ms = 0; ms < 4; ++ms)                                             \
        _Pragma("unroll")                                                      \
        for (int ns = 0; ns < 4; ++ns)                                         \
            acc[ms][ns] = __builtin_amdgcn_mfma_f32_16x16x32_bf16(             \
                af[ms], bfr[ns], acc[ms][ns], 0, 0, 0);                        \
} while (0)

    QSTAGE(0, 0);
    __syncthreads();                            // buf0 ready

    for (int k0 = 0; k0 < 512; k0 += 64) {
        QSTAGE(1, k0 + 32);                     // prefetch odd step
        QCOMP(0);
        __syncthreads();                        // odd staged; buf0 free
        if (k0 + 64 < 512) QSTAGE(0, k0 + 64);  // prefetch next even step
        QCOMP(1);
        __syncthreads();                        // even staged; buf1 free
    }

#undef QSTAGE
#undef QCOMP

    const int sec = m0 >> 9;    // 0=q,1=k,2=v (uniform per block)
#pragma unroll
    for (int ms = 0; ms < 4; ++ms) {
        const int f0 = m0 + mrow + ms * 16 + quad * 4;   // 4 consecutive feats
        const int hh = (f0 & 511) >> 6, j0 = f0 & 63;    // head, 4-aligned col
        f32x4 bb = *(const f32x4*)(bias + f0);
        if (sec == 0) bb = bb * QSCALE;
#pragma unroll
        for (int ns = 0; ns < 4; ++ns) {
            const int tcol = n0 + ncol + ns * 16 + r16;
            const int bi = tcol >> 10;
            const int tg = (tcol & 1023) + (src << 10);
            if (sec == 2) {                 // V: transposed + window-permuted
                const int r = tg & 31;
                const int pos = 2 * r - (r & 3) - ((r >> 4) * 28);
                const int tgp = (tg & ~31) + pos;
                unsigned short* vbase =
                    vtb + (((size_t)((bi * 8 + hh) * 64 + j0)) << 11) + tgp;
#pragma unroll
                for (int i = 0; i < 4; ++i)
                    vbase[(size_t)i << 11] = f2b(acc[ms][ns][i] + bb[i]);
            } else {
                unsigned short* dst = (sec == 0) ? qb : kb;
                bf16x4 pk;
#pragma unroll
                for (int i = 0; i < 4; ++i)
                    pk[i] = (short)f2b(acc[ms][ns][i] + bb[i]);
                *(bf16x4*)(dst + (((size_t)((bi * 8 + hh) * 2048 + tg)) << 6) + j0) = pk;
            }
        }
    }
}

// ---------------------------------------------------------------------------
// attn: round-8/9 verified kernel, byte-identical (setprio restored). S^T
// flash, exp2 domain, 4-buffer LDS pairing: 2 tiles staged + 2 computed per
// barrier interval (17 barriers). Block 256 thr = 4 waves; block = 128
// queries (32/wave) of one bh. 64-key tiles, XOR swizzles both-sides, l via
// ones-A MFMA, direct write. Grid 512 = 32 bh x 16 qtiles, XCD-swizzled;
// LDS 72KB, 2 blocks/CU.
// ---------------------------------------------------------------------------

// stage K+V chunks j = w*2, w*2+1 of tile T into buffer BB
#define STAGE(BB, T) do {                                                      \
    _Pragma("unroll")                                                          \
    for (int r_ = 0; r_ < 2; ++r_) {                                           \
        const int j_ = (w << 1) + r_;                                          \
        const int row_ = (j_ << 3) + rofs;                                     \
        glds16(Kg + (size_t)(((T) << 6) + row_) * 64 + lsw,                    \
               &Kl[BB][(j_ << 9) + lane * 8]);                                 \
        glds16(Vg + (size_t)row_ * 2048 + ((T) << 6) + lsw,                    \
               &Vl[BB][(j_ << 9) + lane * 8]);                                 \
    }                                                                          \
} while (0)

#define DOG(G, TQ, PF) do {                                                    \
    f32x4 s0_ = fz, s1_ = fz;                                                  \
    __builtin_amdgcn_s_setprio(1);                                             \
    s0_ = __builtin_amdgcn_mfma_f32_16x16x32_bf16(ka00, qf[G][0], s0_, 0, 0, 0); \
    s0_ = __builtin_amdgcn_mfma_f32_16x16x32_bf16(ka01, qf[G][1], s0_, 0, 0, 0); \
    s1_ = __builtin_amdgcn_mfma_f32_16x16x32_bf16(ka10, qf[G][0], s1_, 0, 0, 0); \
    s1_ = __builtin_amdgcn_mfma_f32_16x16x32_bf16(ka11, qf[G][1], s1_, 0, 0, 0); \
    __builtin_amdgcn_s_setprio(0);                                             \
    float e_[8];                                                               \
    _Pragma("unroll")                                                          \
    for (int i_ = 0; i_ < 4; ++i_) {                                           \
        float a0_ = ((TQ) >= tk0[i_]) ? s0_[i_] : -1e9f;                       \
        float a1_ = ((TQ) >= tk1[i_]) ? s1_[i_] : -1e9f;                       \
        e_[i_]     = __builtin_amdgcn_exp2f(a0_);                              \
        e_[4 + i_] = __builtin_amdgcn_exp2f(a1_);                              \
    }                                                                          \
    union { unsigned int d[4]; bf16x8 v; } pu_;                                \
    pu_.d[0] = __builtin_amdgcn_perm(fbits(e_[1]), fbits(e_[0]), 0x07060302u); \
    pu_.d[1] = __builtin_amdgcn_perm(fbits(e_[3]), fbits(e_[2]), 0x07060302u); \
    pu_.d[2] = __builtin_amdgcn_perm(fbits(e_[5]), fbits(e_[4]), 0x07060302u); \
    pu_.d[3] = __builtin_amdgcn_perm(fbits(e_[7]), fbits(e_[6]), 0x07060302u); \
    PF = pu_.v;                                                                \
    al[G] = __builtin_amdgcn_mfma_f32_16x16x32_bf16(ones, PF, al[G], 0, 0, 0); \
} while (0)

// one 64-key tile T from buffer BB: two 32-key windows
#define DOTILE(BB, T) do {                                                     \
    const unsigned short* Kb_ = Kl[BB];                                        \
    const unsigned short* Vb_ = Vl[BB];                                        \
    _Pragma("unroll")                                                          \
    for (int c_ = 0; c_ < 2; ++c_) {                                           \
        bf16x8 ka00 = *(const bf16x8*)(Kb_ + (c_ * 32 + r16) * 64 + ((quad ^ rsx) << 3));        \
        bf16x8 ka01 = *(const bf16x8*)(Kb_ + (c_ * 32 + r16) * 64 + (((quad + 4) ^ rsx) << 3));  \
        bf16x8 ka10 = *(const bf16x8*)(Kb_ + (c_ * 32 + 16 + r16) * 64 + ((quad ^ rsx) << 3));   \
        bf16x8 ka11 = *(const bf16x8*)(Kb_ + (c_ * 32 + 16 + r16) * 64 + (((quad + 4) ^ rsx) << 3)); \
        i32x4 tk0 = *(const i32x4*)(Ts + ((T) << 6) + c_ * 32 + quad * 4);     \
        i32x4 tk1 = *(const i32x4*)(Ts + ((T) << 6) + c_ * 32 + 16 + quad * 4);\
        const int vs_ = ((4 * c_ + quad) ^ rsx) << 3;                          \
        bf16x8 va0 = *(const bf16x8*)(Vb_ + (r16) * 64 + vs_);                 \
        bf16x8 va1 = *(const bf16x8*)(Vb_ + (16 + r16) * 64 + vs_);            \
        bf16x8 va2 = *(const bf16x8*)(Vb_ + (32 + r16) * 64 + vs_);            \
        bf16x8 va3 = *(const bf16x8*)(Vb_ + (48 + r16) * 64 + vs_);            \
        bf16x8 pf0, pf1;                                                       \
        DOG(0, tq0, pf0);                                                      \
        DOG(1, tq1, pf1);                                                      \
        __builtin_amdgcn_s_setprio(1);                                         \
        ot[0][0] = __builtin_amdgcn_mfma_f32_16x16x32_bf16(va0, pf0, ot[0][0], 0, 0, 0); \
        ot[1][0] = __builtin_amdgcn_mfma_f32_16x16x32_bf16(va0, pf1, ot[1][0], 0, 0, 0); \
        ot[0][1] = __builtin_amdgcn_mfma_f32_16x16x32_bf16(va1, pf0, ot[0][1], 0, 0, 0); \
        ot[1][1] = __builtin_amdgcn_mfma_f32_16x16x32_bf16(va1, pf1, ot[1][1], 0, 0, 0); \
        ot[0][2] = __builtin_amdgcn_mfma_f32_16x16x32_bf16(va2, pf0, ot[0][2], 0, 0, 0); \
        ot[1][2] = __builtin_amdgcn_mfma_f32_16x16x32_bf16(va2, pf1, ot[1][2], 0, 0, 0); \
        ot[0][3] = __builtin_amdgcn_mfma_f32_16x16x32_bf16(va3, pf0, ot[0][3], 0, 0, 0); \
        ot[1][3] = __builtin_amdgcn_mfma_f32_16x16x32_bf16(va3, pf1, ot[1][3], 0, 0, 0); \
        __builtin_amdgcn_s_setprio(0);                                         \
    }                                                                          \
} while (0)

__global__ __launch_bounds__(256, 2)
void attn_kernel(const unsigned short* __restrict__ qb,
                 const unsigned short* __restrict__ kb,
                 const unsigned short* __restrict__ vt,
                 const int* __restrict__ t_self, const int* __restrict__ t_cross,
                 unsigned short* __restrict__ y)
{
    const int bid = blockIdx.x;
    const int bh = ((bid & 7) << 2) | ((bid >> 3) & 3);   // XCD-local bh group
    const int qt = bid >> 5;                              // 0..15, 128 q each
    const int b = bh >> 3, h = bh & 7;
    const int tid = threadIdx.x, w = tid >> 6, lane = tid & 63;
    const int quad = lane >> 4, r16 = lane & 15;
    const int rofs = lane >> 3;                 // staging row-within-chunk
    const int lsw  = ((lane & 7) ^ rofs) << 3;  // pre-swizzled source slot (shorts)
    const int rsx  = r16 & 7;                   // read-side swizzle term

    const unsigned short* Q  = qb + (size_t)bh * 131072;
    const unsigned short* Kg = kb + (size_t)bh * 131072;
    const unsigned short* Vg = vt + (size_t)bh * 131072;
    const int* tsb = t_self + b * 1024;
    const int* tcb = t_cross + b * 1024;

    __shared__ unsigned short Kl[4][4096];   // 8KB per buffer, swizzled
    __shared__ unsigned short Vl[4][4096];   // 8KB per buffer, swizzled
    __shared__ int Ts[2048];                 // all key times (absolute)

    // stage all key times once: 8 x glds16 (2 per wave)
#pragma unroll
    for (int r = 0; r < 2; ++r) {
        const int sg = (w << 1) + r;
        const int* src = (sg < 4) ? (tsb + sg * 256) : (tcb + (sg - 4) * 256);
        glds16i(src + lane * 4, Ts + sg * 256 + lane * 4);
    }

    const int q0w = qt * 128 + w * 32;          // this wave's 32 queries
    bf16x8 qf[2][2];
#pragma unroll
    for (int g = 0; g < 2; ++g)
#pragma unroll
        for (int ks = 0; ks < 2; ++ks)
            qf[g][ks] = *(const bf16x8*)(Q + (size_t)(q0w + g * 16 + r16) * 64
                                           + ks * 32 + quad * 8);
    const int* tqp = (q0w < 1024) ? (tsb + q0w) : (tcb + (q0w - 1024));
    const int tq0 = tqp[r16];
    const int tq1 = tqp[16 + r16];

    const f32x4 fz = {0.f, 0.f, 0.f, 0.f};
    f32x4 ot[2][4], al[2];
#pragma unroll
    for (int g = 0; g < 2; ++g) {
        al[g] = fz;
#pragma unroll
        for (int nt = 0; nt < 4; ++nt) ot[g][nt] = fz;
    }
    const bf16x8 ones = {(short)0x3F80, (short)0x3F80, (short)0x3F80, (short)0x3F80,
                         (short)0x3F80, (short)0x3F80, (short)0x3F80, (short)0x3F80};

    STAGE(0, 0);
    STAGE(1, 1);
    __syncthreads();                            // times + tiles 0,1 ready

    for (int T = 0; T < 32; T += 4) {
        STAGE(2, T + 2);                        // prefetch next pair
        STAGE(3, T + 3);
        DOTILE(0, T);
        DOTILE(1, T + 1);
        __syncthreads();                        // pair {2,3} staged; {0,1} free
        if (T + 4 < 32) {
            STAGE(0, T + 4);
            STAGE(1, T + 5);
        }
        DOTILE(2, T + 2);
        DOTILE(3, T + 3);
        __syncthreads();                        // pair {0,1} staged; {2,3} free
    }

    // epilogue: normalize and write y directly (no cross-wave merge)
#pragma unroll
    for (int g = 0; g < 2; ++g) {
        const float l = al[g][0];
        const float inv = (l > 0.f) ? (1.f / l) : 0.f;
        const size_t base = (((size_t)(b * 2048 + q0w + g * 16 + r16)) << 9) + h * 64;
#pragma unroll
        for (int nt = 0; nt < 4; ++nt) {
            bf16x4 pk;
#pragma unroll
            for (int i = 0; i < 4; ++i) pk[i] = (short)f2b(ot[g][nt][i] * inv);
            *(bf16x4*)(y + base + nt * 16 + quad * 4) = pk;
        }
    }
}

#undef STAGE
#undef DOG
#undef DOTILE

// ---------------------------------------------------------------------------
// proj (swapped orientation): D[feature][token] = wtp-rows . Y-rows^T + b.
// 64(features) x 128(tokens) tile -> grid 512. f32x4 stores, XOR k-slot
// swizzle, double-buffered LDS prefetch (24KB).
// ---------------------------------------------------------------------------
__global__ __launch_bounds__(256)
void proj_kernel(const unsigned short* __restrict__ X,
                 const unsigned short* __restrict__ Wt,
                 const float* __restrict__ bias,
                 float* __restrict__ out)
{
    const int m0 = blockIdx.y * 64;     // feature tile (8)
    const int n0 = blockIdx.x * 128;    // token tile (64)
    __shared__ unsigned short As[2][64 * 32];    // A = wtp (features), 4KB ea
    __shared__ unsigned short Bs[2][128 * 32];   // B = Y (tokens),     8KB ea

    const int tid = threadIdx.x, lane = tid & 63, w = tid >> 6;
    const int quad = lane >> 4, r16 = lane & 15;
    const int mrow = (w >> 1) * 32, ncol = (w & 1) * 64;

    const f32x4 fz = {0.f, 0.f, 0.f, 0.f};
    f32x4 acc[2][4];
#pragma unroll
    for (int a = 0; a < 2; ++a)
#pragma unroll
        for (int b = 0; b < 4; ++b) acc[a][b] = fz;

    const int rofs = lane >> 2;
    const int kswz = (((lane & 3) ^ ((lane >> 3) & 3))) * 8;
    const unsigned short* gA = Wt + (size_t)(m0 + w * 16 + rofs) * 512 + kswz;
    const unsigned short* gB = X + (size_t)(n0 + (w << 1) * 16 + rofs) * 512 + kswz;
    const int lofsA = w * 512 + lane * 8;
    const int lofsB = (w << 1) * 512 + lane * 8;
    const int rsw = (r16 >> 1) & 3;

#define PSTAGE(BB, K0) do {                                                    \
    glds16(gA + (K0), &As[BB][lofsA]);                                         \
    glds16(gB + (K0), &Bs[BB][lofsB]);                                         \
    glds16(gB + 16 * 512 + (K0), &Bs[BB][lofsB + 512]);                        \
} while (0)

#define PCOMP(BB) do {                                                         \
    bf16x8 af[2], bfr[4];                                                      \
    _Pragma("unroll")                                                          \
    for (int ms = 0; ms < 2; ++ms)                                             \
        af[ms] = *(const bf16x8*)(&As[BB][(mrow + ms * 16 + r16) * 32          \
                                          + (quad ^ rsw) * 8]);                \
    _Pragma("unroll")                                                          \
    for (int ns = 0; ns < 4; ++ns)                                             \
        bfr[ns] = *(const bf16x8*)(&Bs[BB][(ncol + ns * 16 + r16) * 32         \
                                           + (quad ^ rsw) * 8]);               \
    _Pragma("unroll")                                                          \
    for (int ms = 0; ms < 2; ++ms)                                             \
        _Pragma("unroll")                                                      \
        for (int ns = 0; ns < 4; ++ns)                                         \
            acc[ms][ns] = __builtin_amdgcn_mfma_f32_16x16x32_bf16(             \
                af[ms], bfr[ns], acc[ms][ns], 0, 0, 0);                        \
} while (0)

    PSTAGE(0, 0);
    __syncthreads();

    for (int k0 = 0; k0 < 512; k0 += 64) {
        PSTAGE(1, k0 + 32);
        PCOMP(0);
        __syncthreads();
        if (k0 + 64 < 512) PSTAGE(0, k0 + 64);
        PCOMP(1);
        __syncthreads();
    }

#undef PSTAGE
#undef PCOMP

#pragma unroll
    for (int ms = 0; ms < 2; ++ms) {
        const int f0 = m0 + mrow + ms * 16 + quad * 4;   // 4 consecutive feats
        f32x4 bb = *(const f32x4*)(bias + f0);
#pragma unroll
        for (int ns = 0; ns < 4; ++ns) {
            const int tok = n0 + ncol + ns * 16 + r16;
            const int bi = tok >> 11, t = tok & 2047;
            const size_t rowbase = (t < 1024)
                ? ((size_t)bi * 1024 + t) * 512
                : (size_t)2097152 + ((size_t)bi * 1024 + (t - 1024)) * 512;
            f32x4 v;
#pragma unroll
            for (int i = 0; i < 4; ++i) v[i] = acc[ms][ns][i] + bb[i];
            *(f32x4*)(out + rowbase + f0) = v;
        }
    }
}

// ---------------------------------------------------------------------------
extern "C" void kernel_launch(void* const* d_in, const int* in_sizes, int n_in,
                              void* d_out, int out_size, void* d_ws, size_t ws_size,
                              hipStream_t stream)
{
    const float* self_seq  = (const float*)d_in[0];
    const float* cross_seq = (const float*)d_in[1];
    const int*   t_self    = (const int*)d_in[2];
    const int*   t_cross   = (const int*)d_in[3];
    const float* W_self    = (const float*)d_in[4];
    const float* b_self    = (const float*)d_in[5];
    const float* W_cross   = (const float*)d_in[6];
    const float* b_cross   = (const float*)d_in[7];
    const float* W_proj    = (const float*)d_in[8];
    const float* b_proj    = (const float*)d_in[9];
    float* out = (float*)d_out;

    // ws (32 MB): q, k, vt, y (4 x 4,194,304 bf16).
    // d_out (33.5 MB fp32) slack holds xb (8 MB) + wt (3 MB) + wtp (0.5 MB)
    // as scratch until proj overwrites everything.
    unsigned short* qbuf = (unsigned short*)d_ws;
    unsigned short* kbuf = qbuf + 4194304;
    unsigned short* vtb  = kbuf + 4194304;
    unsigned short* ybuf = vtb + 4194304;
    unsigned short* xb   = (unsigned short*)d_out;
    unsigned short* wt   = xb + 4194304;
    unsigned short* wtp  = wt + 1572864;

    prep_kernel<<<dim3(2496), 256, 0, stream>>>(
        self_seq, cross_seq, W_self, W_cross, W_proj, xb, wt, wtp);

    qkv_kernel<<<dim3(32, 12, 2), 256, 0, stream>>>(
        xb, wt, b_self, b_cross, qbuf, kbuf, vtb);

    attn_kernel<<<dim3(512), 256, 0, stream>>>(
        qbuf, kbuf, vtb, t_self, t_cross, ybuf);

    proj_kernel<<<dim3(64, 8), 256, 0, stream>>>(
        ybuf, wtp, b_proj, out);
}